// Round 3
// baseline (855.776 us; speedup 1.0000x reference)
//
#include <hip/hip_runtime.h>
#include <hip/hip_bf16.h>

// Problem constants (fixed by the reference)
#define DD   768
#define TT   1024
#define BBATCH 16
#define NROWS (BBATCH * TT)   // 16384
#define HIDN 3072
#define HH 32
#define WW 32
#define DW  (DD * DD)         // 589824
#define DH  (DD * HIDN)       // 2359296

typedef float  floatx4 __attribute__((ext_vector_type(4)));
typedef __bf16 bf16x8  __attribute__((ext_vector_type(8)));

__device__ __forceinline__ float bf2f(__hip_bfloat16 v) { return __bfloat162float(v); }
__device__ __forceinline__ __hip_bfloat16 f2bf(float v) { return __float2bfloat16(v); }
__device__ __forceinline__ float toF(__hip_bfloat16 v) { return __bfloat162float(v); }
__device__ __forceinline__ float toF(float v) { return v; }

// ---------------------------------------------------------------------------
// fp32 -> bf16 weight conversion (per-launch; d_ws is re-poisoned every call)
// ---------------------------------------------------------------------------
__global__ __launch_bounds__(256)
void cvt_k(const float* __restrict__ s, __hip_bfloat16* __restrict__ d, int n)
{
    const int i = (blockIdx.x * 256 + threadIdx.x) * 4;
    if (i >= n) return;
    const float4 v = *reinterpret_cast<const float4*>(s + i);
    __hip_bfloat16 o[4] = {f2bf(v.x), f2bf(v.y), f2bf(v.z), f2bf(v.w)};
    *reinterpret_cast<ushort4*>(d + i) = *reinterpret_cast<const ushort4*>(o);
}

// ---------------------------------------------------------------------------
// Per-row LN stats: mean + rstd (768 cols, 256 threads x 3)
// ---------------------------------------------------------------------------
template <typename TIN>
__global__ __launch_bounds__(256)
void ln_stats_k(const TIN* __restrict__ x,
                float* __restrict__ mean, float* __restrict__ rstd)
{
    const int row = blockIdx.x, tid = threadIdx.x;
    const int lane = tid & 63, wid = tid >> 6;
    const TIN* xr = x + (size_t)row * DD;
    float s1 = 0.f, s2 = 0.f;
#pragma unroll
    for (int i = 0; i < 3; ++i) {
        const float v = toF(xr[tid + i * 256]);
        s1 += v; s2 += v * v;
    }
#pragma unroll
    for (int off = 32; off > 0; off >>= 1) {
        s1 += __shfl_down(s1, off);
        s2 += __shfl_down(s2, off);
    }
    __shared__ float sh[8];
    if (lane == 0) { sh[wid] = s1; sh[4 + wid] = s2; }
    __syncthreads();
    if (tid == 0) {
        s1 = sh[0] + sh[1] + sh[2] + sh[3];
        s2 = sh[4] + sh[5] + sh[6] + sh[7];
        const float m = s1 * (1.f / DD);
        mean[row] = m;
        rstd[row] = rsqrtf(s2 * (1.f / DD) - m * m + 1e-5f);
    }
}

// ---------------------------------------------------------------------------
// LN-on-the-fly + q_shift + token-mix, bf16 outputs (GEMM A operands)
// ---------------------------------------------------------------------------
template <typename TIN>
__device__ __forceinline__ float ln_at(const TIN* __restrict__ x,
                                       const float* __restrict__ mean,
                                       const float* __restrict__ rstd,
                                       const float* __restrict__ g,
                                       const float* __restrict__ b,
                                       int grow, int c)
{
    return (toF(x[(size_t)grow * DD + c]) - mean[grow]) * rstd[grow] * g[c] + b[c];
}

template <typename TIN, int NOUT>
__global__ __launch_bounds__(256)
void mix_k(const TIN* __restrict__ x,
           const float* __restrict__ mean, const float* __restrict__ rstd,
           const float* __restrict__ g, const float* __restrict__ b,
           const float* __restrict__ muk,
           const float* __restrict__ muv,   // unused if NOUT==2
           const float* __restrict__ mur,
           __hip_bfloat16* __restrict__ xk,
           __hip_bfloat16* __restrict__ xv, // unused if NOUT==2
           __hip_bfloat16* __restrict__ xr)
{
    const size_t idx = (size_t)blockIdx.x * 256 + threadIdx.x;
    const int c  = (int)(idx % DD);
    const int n  = (int)((idx / DD) % TT);
    const int bb = (int)(idx / ((size_t)DD * TT));
    const int y = n >> 5, xp = n & 31;
    const int grow = bb * TT + n;

    const float av = ln_at(x, mean, rstd, g, b, grow, c);

    // quad-directional shift on the normalized tensor (zero-pad OOB)
    const int grp = c / (DD / 4);
    int ny = y, nx = xp; bool ok;
    if      (grp == 0) { nx = xp - 1; ok = xp > 0;      }
    else if (grp == 1) { nx = xp + 1; ok = xp < WW - 1; }
    else if (grp == 2) { ny = y - 1;  ok = y > 0;       }
    else               { ny = y + 1;  ok = y < HH - 1;  }
    const float sx = ok ? ln_at(x, mean, rstd, g, b, bb * TT + ny * WW + nx, c) : 0.f;

    const float mk = muk[c], mr = mur[c];
    xk[idx] = f2bf(av * mk + sx * (1.f - mk));
    xr[idx] = f2bf(av * mr + sx * (1.f - mr));
    if (NOUT == 3) {
        const float mv = muv[c];
        xv[idx] = f2bf(av * mv + sx * (1.f - mv));
    }
}

// ---------------------------------------------------------------------------
// GEMM: C[M, Nn] = A[M, K packed] @ W[Nn rows, stride Wstr]^T, bf16 in,
// fp32 accum. 128x128 tile, 4 waves (2x2 of 64x64), BK=64,
// mfma_f32_16x16x32_bf16. LDS row stride 72 bf16 (144 B): 16B-aligned
// ds_read_b128, only 2-way bank alias (free per m136).
// MODE: 0=bf16(acc), 1=bf16(sigmoid), 2=bf16(acc + xf32), 3=bf16(relu^2),
//       4=f32 out = h + s*acc + x, 5=f32 out += s*acc
// ---------------------------------------------------------------------------
#define BM 128
#define BN 128
#define BKK 64
#define LSTR 72

template <int MODE>
__global__ __launch_bounds__(256, 2)
void gemm_bt(const __hip_bfloat16* __restrict__ A,
             const __hip_bfloat16* __restrict__ W,
             int K, int Wstr, int Nn,
             __hip_bfloat16* __restrict__ outB,
             float* __restrict__ outF,
             const __hip_bfloat16* __restrict__ auxS,  // sigmoid gate [4,5]
             const __hip_bfloat16* __restrict__ auxH,  // h bf16       [4]
             const float* __restrict__ auxX)           // x fp32       [2,4]
{
    __shared__ __align__(16) unsigned short lA[BM * LSTR];
    __shared__ __align__(16) unsigned short lB[BN * LSTR];

    const int tid  = threadIdx.x;
    const int bm   = blockIdx.x, bn = blockIdx.y;
    const int lane = tid & 63, wid = tid >> 6;
    const int l15  = lane & 15, quad = lane >> 4;
    const int m0   = (wid & 1) * 64;
    const int n0   = (wid >> 1) * 64;

    floatx4 acc[4][4];
#pragma unroll
    for (int i = 0; i < 4; ++i)
#pragma unroll
        for (int j = 0; j < 4; ++j)
            acc[i][j] = floatx4{0.f, 0.f, 0.f, 0.f};

    for (int k0 = 0; k0 < K; k0 += BKK) {
#pragma unroll
        for (int it = 0; it < 4; ++it) {
            const int chunk = tid + it * 256;   // 0..1023
            const int r  = chunk >> 3;          // 0..127
            const int c8 = chunk & 7;           // 8 bf16 each
            const uint4 va = *reinterpret_cast<const uint4*>(
                A + (size_t)(bm * BM + r) * K + k0 + c8 * 8);
            const uint4 vb = *reinterpret_cast<const uint4*>(
                W + (size_t)(bn * BN + r) * Wstr + k0 + c8 * 8);
            *reinterpret_cast<uint4*>(&lA[r * LSTR + c8 * 8]) = va;
            *reinterpret_cast<uint4*>(&lB[r * LSTR + c8 * 8]) = vb;
        }
        __syncthreads();
#pragma unroll
        for (int kk = 0; kk < BKK; kk += 32) {
            bf16x8 af[4], bfr[4];
#pragma unroll
            for (int i = 0; i < 4; ++i)
                af[i] = *reinterpret_cast<const bf16x8*>(
                    &lA[(m0 + i * 16 + l15) * LSTR + kk + quad * 8]);
#pragma unroll
            for (int j = 0; j < 4; ++j)
                bfr[j] = *reinterpret_cast<const bf16x8*>(
                    &lB[(n0 + j * 16 + l15) * LSTR + kk + quad * 8]);
#pragma unroll
            for (int i = 0; i < 4; ++i)
#pragma unroll
                for (int j = 0; j < 4; ++j)
                    acc[i][j] = __builtin_amdgcn_mfma_f32_16x16x32_bf16(
                        af[i], bfr[j], acc[i][j], 0, 0, 0);
        }
        __syncthreads();
    }

    // Epilogue. C/D layout: col = lane&15, row = quad*4 + reg  [m89/m91]
#pragma unroll
    for (int i = 0; i < 4; ++i) {
#pragma unroll
        for (int j = 0; j < 4; ++j) {
#pragma unroll
            for (int r = 0; r < 4; ++r) {
                const int grow = bm * BM + m0 + i * 16 + quad * 4 + r;
                const int gcol = bn * BN + n0 + j * 16 + l15;
                const size_t idx = (size_t)grow * Nn + gcol;
                const float v = acc[i][j][r];
                if (MODE == 0) {
                    outB[idx] = f2bf(v);
                } else if (MODE == 1) {
                    outB[idx] = f2bf(1.f / (1.f + __expf(-v)));
                } else if (MODE == 2) {
                    outB[idx] = f2bf(v + auxX[idx]);
                } else if (MODE == 3) {
                    const float t = fmaxf(v, 0.f);
                    outB[idx] = f2bf(t * t);
                } else if (MODE == 4) {
                    outF[idx] = bf2f(auxH[idx]) + bf2f(auxS[idx]) * v + auxX[idx];
                } else {
                    outF[idx] += bf2f(auxS[idx]) * v;
                }
            }
        }
    }
}

// ---------------------------------------------------------------------------
// WKV scan (fused with r-gating): one thread per (batch, channel).
// ---------------------------------------------------------------------------
__global__ __launch_bounds__(64)
void wkv_k(const float* __restrict__ w_log,
           const float* __restrict__ u,
           const __hip_bfloat16* __restrict__ k,
           const __hip_bfloat16* __restrict__ v,
           const __hip_bfloat16* __restrict__ r,
           __hip_bfloat16* __restrict__ rw)
{
    const int idx = blockIdx.x * 64 + threadIdx.x;  // 0..B*D-1
    const int c = idx % DD, bb = idx / DD;
    const float w  = -__expf(w_log[c]);
    const float uu = u[c];
    const size_t base = (size_t)bb * TT * DD + c;
    const __hip_bfloat16* kp = k  + base;
    const __hip_bfloat16* vp = v  + base;
    const __hip_bfloat16* rp = r  + base;
    __hip_bfloat16*       op = rw + base;

    float aa = 0.f, bbv = 0.f, pp = -1e30f;
    float kt = bf2f(kp[0]), vt = bf2f(vp[0]), rt = bf2f(rp[0]);
    for (int t = 0; t < TT; ++t) {
        float kn = 0.f, vn = 0.f, rn = 0.f;
        if (t + 1 < TT) {
            const size_t o = (size_t)(t + 1) * DD;
            kn = bf2f(kp[o]); vn = bf2f(vp[o]); rn = bf2f(rp[o]);
        }
        const float ww = uu + kt;
        const float p  = fmaxf(pp, ww);
        const float e1 = __expf(pp - p);
        const float e2 = __expf(ww - p);
        const float o  = (e1 * aa + e2 * vt) / (e1 * bbv + e2);
        op[(size_t)t * DD] = f2bf(rt * o);
        const float ww2 = pp + w;
        const float p2  = fmaxf(ww2, kt);
        const float e1b = __expf(ww2 - p2);
        const float e2b = __expf(kt - p2);
        aa  = e1b * aa + e2b * vt;
        bbv = e1b * bbv + e2b;
        pp  = p2;
        kt = kn; vt = vn; rt = rn;
    }
}

// ---------------------------------------------------------------------------
extern "C" void kernel_launch(void* const* d_in, const int* in_sizes, int n_in,
                              void* d_out, int out_size, void* d_ws, size_t ws_size,
                              hipStream_t stream)
{
    (void)in_sizes; (void)n_in; (void)out_size;
    const float* x     = (const float*)d_in[0];
    // d_in[1]=H, d_in[2]=W (compile-time constants 32x32)
    const float* ln1_g = (const float*)d_in[3];
    const float* ln1_b = (const float*)d_in[4];
    const float* ln2_g = (const float*)d_in[5];
    const float* ln2_b = (const float*)d_in[6];
    const float* mu_k  = (const float*)d_in[7];
    const float* mu_v  = (const float*)d_in[8];
    const float* mu_r  = (const float*)d_in[9];
    const float* w_log = (const float*)d_in[10];
    const float* u     = (const float*)d_in[11];
    const float* Wk    = (const float*)d_in[12];
    const float* Wv    = (const float*)d_in[13];
    const float* Wr    = (const float*)d_in[14];
    const float* Wo    = (const float*)d_in[15];
    const float* cmu_k = (const float*)d_in[16];
    const float* cmu_r = (const float*)d_in[17];
    const float* Ck    = (const float*)d_in[18];
    const float* Cv    = (const float*)d_in[19];
    const float* Cr    = (const float*)d_in[20];
    float* out = (float*)d_out;

    // ---- workspace: 5 bf16 ND slots + bf16 weights + stats = 141.3 MB ----
    // (round-2 ran with NEED=151.2 MB => ws_size >= 151.2 MB, so this fits)
    // slot timeline: R0: xk -> r -> xk2 | R1: xv -> rw -> xr2
    //                R2: xr -> h        | R3: k  -> cr  | R4: v -> kk(quarters)
    const size_t ND = (size_t)NROWS * DD;   // 12,582,912 elements
    const size_t SL = ND * 2;               // 25,165,824 B per bf16 slot
    const size_t WBYTES = (size_t)(5 * DW + 2 * DH) * 2;  // 15,335,424
    const size_t NEED = 5 * SL + WBYTES + 2 * (size_t)NROWS * sizeof(float);
    if (ws_size < NEED) return;  // diagnostic: absmax-fail instead of fault

    char* w = (char*)d_ws;
    __hip_bfloat16* R0 = (__hip_bfloat16*)(w);
    __hip_bfloat16* R1 = (__hip_bfloat16*)(w + 1 * SL);
    __hip_bfloat16* R2 = (__hip_bfloat16*)(w + 2 * SL);
    __hip_bfloat16* R3 = (__hip_bfloat16*)(w + 3 * SL);
    __hip_bfloat16* R4 = (__hip_bfloat16*)(w + 4 * SL);
    __hip_bfloat16* WkB = (__hip_bfloat16*)(w + 5 * SL);
    __hip_bfloat16* WvB = WkB + DW;
    __hip_bfloat16* WrB = WvB + DW;
    __hip_bfloat16* WoB = WrB + DW;
    __hip_bfloat16* CrB = WoB + DW;
    __hip_bfloat16* CkB = CrB + DW;
    __hip_bfloat16* CvB = CkB + DH;
    float* meanB = (float*)(w + 5 * SL + WBYTES);
    float* rstdB = meanB + NROWS;

    const int EW_GRID = (int)(ND / 256);      // 49152
    const dim3 g768(NROWS / BM, DD / BN);     // (128, 6)
    const int CB_W = DW / 4 / 256;            // 576
    const int CB_H = DH / 4 / 256;            // 2304

    // ---- weight conversion ----
    cvt_k<<<CB_W, 256, 0, stream>>>(Wk, WkB, DW);
    cvt_k<<<CB_W, 256, 0, stream>>>(Wv, WvB, DW);
    cvt_k<<<CB_W, 256, 0, stream>>>(Wr, WrB, DW);
    cvt_k<<<CB_W, 256, 0, stream>>>(Wo, WoB, DW);
    cvt_k<<<CB_W, 256, 0, stream>>>(Cr, CrB, DW);
    cvt_k<<<CB_H, 256, 0, stream>>>(Ck, CkB, DH);
    cvt_k<<<CB_H, 256, 0, stream>>>(Cv, CvB, DH);

    // ---- spatial mix ----
    ln_stats_k<float><<<NROWS, 256, 0, stream>>>(x, meanB, rstdB);
    mix_k<float, 3><<<EW_GRID, 256, 0, stream>>>(x, meanB, rstdB, ln1_g, ln1_b,
                                                 mu_k, mu_v, mu_r, R0, R1, R2);
    gemm_bt<0><<<g768, 256, 0, stream>>>(R0, WkB, DD, DD, DD, R3, nullptr, nullptr, nullptr, nullptr); // k
    gemm_bt<0><<<g768, 256, 0, stream>>>(R1, WvB, DD, DD, DD, R4, nullptr, nullptr, nullptr, nullptr); // v
    gemm_bt<1><<<g768, 256, 0, stream>>>(R2, WrB, DD, DD, DD, R0, nullptr, nullptr, nullptr, nullptr); // r=sigmoid
    wkv_k<<<(BBATCH * DD) / 64, 64, 0, stream>>>(w_log, u, R3, R4, R0, R1);                            // rw
    gemm_bt<2><<<g768, 256, 0, stream>>>(R1, WoB, DD, DD, DD, R2, nullptr, nullptr, nullptr, x);       // h = acc + x

    // ---- channel mix ----
    ln_stats_k<__hip_bfloat16><<<NROWS, 256, 0, stream>>>(R2, meanB, rstdB);
    mix_k<__hip_bfloat16, 2><<<EW_GRID, 256, 0, stream>>>(R2, meanB, rstdB, ln2_g, ln2_b,
                                                          cmu_k, nullptr, cmu_r, R0, nullptr, R1);
    gemm_bt<1><<<g768, 256, 0, stream>>>(R1, CrB, DD, DD, DD, R3, nullptr, nullptr, nullptr, nullptr); // cr=sigmoid
    // FFN in four 768-wide quarters: kk = relu(xk2 @ Ck_q^T)^2 -> out (+)= s*kk@Cv_q^T
#pragma unroll 1
    for (int q = 0; q < 4; ++q) {
        gemm_bt<3><<<g768, 256, 0, stream>>>(R0, CkB + (size_t)q * DW, DD, DD, DD,
                                             R4, nullptr, nullptr, nullptr, nullptr);
        if (q == 0)
            gemm_bt<4><<<g768, 256, 0, stream>>>(R4, CvB + q * DD, DD, HIDN, DD,
                                                 nullptr, out, R3, R2, x);
        else
            gemm_bt<5><<<g768, 256, 0, stream>>>(R4, CvB + q * DD, DD, HIDN, DD,
                                                 nullptr, out, R3, nullptr, nullptr);
    }
}

// Round 4
// 798.643 us; speedup vs baseline: 1.0715x; 1.0715x over previous
//
#include <hip/hip_runtime.h>
#include <hip/hip_bf16.h>

// Problem constants (fixed by the reference)
#define DD   768
#define TT   1024
#define BBATCH 16
#define NROWS (BBATCH * TT)   // 16384
#define HIDN 3072
#define HHALF 1536
#define HH 32
#define WW 32
#define DW  (DD * DD)         // 589824
#define DH  (DD * HIDN)       // 2359296

typedef float  floatx4 __attribute__((ext_vector_type(4)));
typedef __bf16 bf16x8  __attribute__((ext_vector_type(8)));

__device__ __forceinline__ float bf2f(__hip_bfloat16 v) { return __bfloat162float(v); }
__device__ __forceinline__ __hip_bfloat16 f2bf(float v) { return __float2bfloat16(v); }
__device__ __forceinline__ float toF(__hip_bfloat16 v) { return __bfloat162float(v); }
__device__ __forceinline__ float toF(float v) { return v; }

// ---------------------------------------------------------------------------
// fp32 -> bf16 weight conversion (per-launch; d_ws is re-poisoned every call)
// ---------------------------------------------------------------------------
__global__ __launch_bounds__(256)
void cvt_k(const float* __restrict__ s, __hip_bfloat16* __restrict__ d, int n)
{
    const int i = (blockIdx.x * 256 + threadIdx.x) * 4;
    if (i >= n) return;
    const float4 v = *reinterpret_cast<const float4*>(s + i);
    __hip_bfloat16 o[4] = {f2bf(v.x), f2bf(v.y), f2bf(v.z), f2bf(v.w)};
    *reinterpret_cast<ushort4*>(d + i) = *reinterpret_cast<const ushort4*>(o);
}

// ---------------------------------------------------------------------------
// Per-row LN stats: mean + rstd (768 cols, 256 threads x 3)
// ---------------------------------------------------------------------------
template <typename TIN>
__global__ __launch_bounds__(256)
void ln_stats_k(const TIN* __restrict__ x,
                float* __restrict__ mean, float* __restrict__ rstd)
{
    const int row = blockIdx.x, tid = threadIdx.x;
    const int lane = tid & 63, wid = tid >> 6;
    const TIN* xr = x + (size_t)row * DD;
    float s1 = 0.f, s2 = 0.f;
#pragma unroll
    for (int i = 0; i < 3; ++i) {
        const float v = toF(xr[tid + i * 256]);
        s1 += v; s2 += v * v;
    }
#pragma unroll
    for (int off = 32; off > 0; off >>= 1) {
        s1 += __shfl_down(s1, off);
        s2 += __shfl_down(s2, off);
    }
    __shared__ float sh[8];
    if (lane == 0) { sh[wid] = s1; sh[4 + wid] = s2; }
    __syncthreads();
    if (tid == 0) {
        s1 = sh[0] + sh[1] + sh[2] + sh[3];
        s2 = sh[4] + sh[5] + sh[6] + sh[7];
        const float m = s1 * (1.f / DD);
        mean[row] = m;
        rstd[row] = rsqrtf(s2 * (1.f / DD) - m * m + 1e-5f);
    }
}

// ---------------------------------------------------------------------------
// LN-on-the-fly + q_shift + token-mix, bf16 outputs (GEMM A operands)
// ---------------------------------------------------------------------------
template <typename TIN>
__device__ __forceinline__ float ln_at(const TIN* __restrict__ x,
                                       const float* __restrict__ mean,
                                       const float* __restrict__ rstd,
                                       const float* __restrict__ g,
                                       const float* __restrict__ b,
                                       int grow, int c)
{
    return (toF(x[(size_t)grow * DD + c]) - mean[grow]) * rstd[grow] * g[c] + b[c];
}

template <typename TIN, int NOUT>
__global__ __launch_bounds__(256)
void mix_k(const TIN* __restrict__ x,
           const float* __restrict__ mean, const float* __restrict__ rstd,
           const float* __restrict__ g, const float* __restrict__ b,
           const float* __restrict__ muk,
           const float* __restrict__ muv,   // unused if NOUT==2
           const float* __restrict__ mur,
           __hip_bfloat16* __restrict__ xk,
           __hip_bfloat16* __restrict__ xv, // unused if NOUT==2
           __hip_bfloat16* __restrict__ xr)
{
    const size_t idx = (size_t)blockIdx.x * 256 + threadIdx.x;
    const int c  = (int)(idx % DD);
    const int n  = (int)((idx / DD) % TT);
    const int bb = (int)(idx / ((size_t)DD * TT));
    const int y = n >> 5, xp = n & 31;
    const int grow = bb * TT + n;

    const float av = ln_at(x, mean, rstd, g, b, grow, c);

    // quad-directional shift on the normalized tensor (zero-pad OOB)
    const int grp = c / (DD / 4);
    int ny = y, nx = xp; bool ok;
    if      (grp == 0) { nx = xp - 1; ok = xp > 0;      }
    else if (grp == 1) { nx = xp + 1; ok = xp < WW - 1; }
    else if (grp == 2) { ny = y - 1;  ok = y > 0;       }
    else               { ny = y + 1;  ok = y < HH - 1;  }
    const float sx = ok ? ln_at(x, mean, rstd, g, b, bb * TT + ny * WW + nx, c) : 0.f;

    const float mk = muk[c], mr = mur[c];
    xk[idx] = f2bf(av * mk + sx * (1.f - mk));
    xr[idx] = f2bf(av * mr + sx * (1.f - mr));
    if (NOUT == 3) {
        const float mv = muv[c];
        xv[idx] = f2bf(av * mv + sx * (1.f - mv));
    }
}

// ---------------------------------------------------------------------------
// GEMM: C[M, Nn] = A[M, K packed] @ W[Nn rows, stride Wstr]^T, bf16 in,
// fp32 accum. 128x128 tile, 4 waves (2x2 of 64x64), BK=64,
// mfma_f32_16x16x32_bf16. LDS row stride 72 bf16 (144 B): 16B-aligned
// ds_read_b128, only 2-way bank alias (free per m136).
// MODE: 0=bf16(acc), 1=bf16(sigmoid), 2=bf16(acc + xf32), 3=bf16(relu^2),
//       4=f32 out = h + s*acc + x, 5=f32 out += s*acc
// ---------------------------------------------------------------------------
#define BM 128
#define BN 128
#define BKK 64
#define LSTR 72

template <int MODE>
__global__ __launch_bounds__(256, 2)
void gemm_bt(const __hip_bfloat16* __restrict__ A,
             const __hip_bfloat16* __restrict__ W,
             int K, int Wstr, int Nn,
             __hip_bfloat16* __restrict__ outB,
             float* __restrict__ outF,
             const __hip_bfloat16* __restrict__ auxS,  // sigmoid gate [4,5]
             const __hip_bfloat16* __restrict__ auxH,  // h bf16       [4]
             const float* __restrict__ auxX)           // x fp32       [2,4]
{
    __shared__ __align__(16) unsigned short lA[BM * LSTR];
    __shared__ __align__(16) unsigned short lB[BN * LSTR];

    const int tid  = threadIdx.x;
    const int bm   = blockIdx.x, bn = blockIdx.y;
    const int lane = tid & 63, wid = tid >> 6;
    const int l15  = lane & 15, quad = lane >> 4;
    const int m0   = (wid & 1) * 64;
    const int n0   = (wid >> 1) * 64;

    floatx4 acc[4][4];
#pragma unroll
    for (int i = 0; i < 4; ++i)
#pragma unroll
        for (int j = 0; j < 4; ++j)
            acc[i][j] = floatx4{0.f, 0.f, 0.f, 0.f};

    for (int k0 = 0; k0 < K; k0 += BKK) {
#pragma unroll
        for (int it = 0; it < 4; ++it) {
            const int chunk = tid + it * 256;   // 0..1023
            const int r  = chunk >> 3;          // 0..127
            const int c8 = chunk & 7;           // 8 bf16 each
            const uint4 va = *reinterpret_cast<const uint4*>(
                A + (size_t)(bm * BM + r) * K + k0 + c8 * 8);
            const uint4 vb = *reinterpret_cast<const uint4*>(
                W + (size_t)(bn * BN + r) * Wstr + k0 + c8 * 8);
            *reinterpret_cast<uint4*>(&lA[r * LSTR + c8 * 8]) = va;
            *reinterpret_cast<uint4*>(&lB[r * LSTR + c8 * 8]) = vb;
        }
        __syncthreads();
#pragma unroll
        for (int kk = 0; kk < BKK; kk += 32) {
            bf16x8 af[4], bfr[4];
#pragma unroll
            for (int i = 0; i < 4; ++i)
                af[i] = *reinterpret_cast<const bf16x8*>(
                    &lA[(m0 + i * 16 + l15) * LSTR + kk + quad * 8]);
#pragma unroll
            for (int j = 0; j < 4; ++j)
                bfr[j] = *reinterpret_cast<const bf16x8*>(
                    &lB[(n0 + j * 16 + l15) * LSTR + kk + quad * 8]);
#pragma unroll
            for (int i = 0; i < 4; ++i)
#pragma unroll
                for (int j = 0; j < 4; ++j)
                    acc[i][j] = __builtin_amdgcn_mfma_f32_16x16x32_bf16(
                        af[i], bfr[j], acc[i][j], 0, 0, 0);
        }
        __syncthreads();
    }

    // Epilogue. C/D layout: col = lane&15, row = quad*4 + reg  [m89/m91]
#pragma unroll
    for (int i = 0; i < 4; ++i) {
#pragma unroll
        for (int j = 0; j < 4; ++j) {
#pragma unroll
            for (int r = 0; r < 4; ++r) {
                const int grow = bm * BM + m0 + i * 16 + quad * 4 + r;
                const int gcol = bn * BN + n0 + j * 16 + l15;
                const size_t idx = (size_t)grow * Nn + gcol;
                const float v = acc[i][j][r];
                if (MODE == 0) {
                    outB[idx] = f2bf(v);
                } else if (MODE == 1) {
                    outB[idx] = f2bf(1.f / (1.f + __expf(-v)));
                } else if (MODE == 2) {
                    outB[idx] = f2bf(v + auxX[idx]);
                } else if (MODE == 3) {
                    const float t = fmaxf(v, 0.f);
                    outB[idx] = f2bf(t * t);
                } else if (MODE == 4) {
                    outF[idx] = bf2f(auxH[idx]) + bf2f(auxS[idx]) * v + auxX[idx];
                } else {
                    outF[idx] += bf2f(auxS[idx]) * v;
                }
            }
        }
    }
}

// ---------------------------------------------------------------------------
// WKV scan, LDS-staged: block = (batch, 256-channel tile), 256 threads.
// Chunks of CT=32 timesteps; chunk i+1's global loads are issued into
// registers BEFORE computing chunk i, so the ~32*30-cycle serial chain
// covers the load latency. LDS 48 KB single-buffered (regs are the 2nd
// buffer). r-gating fused.
// ---------------------------------------------------------------------------
#define CT 32
#define NC (TT / CT)     // 32
#define CTILE 256

__global__ __launch_bounds__(256)
void wkv_lds_k(const float* __restrict__ w_log, const float* __restrict__ u,
               const __hip_bfloat16* __restrict__ k,
               const __hip_bfloat16* __restrict__ v,
               const __hip_bfloat16* __restrict__ r,
               __hip_bfloat16* __restrict__ rw)
{
    __shared__ __align__(16) unsigned short kb[CT][CTILE];
    __shared__ __align__(16) unsigned short vb[CT][CTILE];
    __shared__ __align__(16) unsigned short rb[CT][CTILE];

    const int tid = threadIdx.x;
    const int ct0 = blockIdx.x * CTILE;   // channel-tile origin (0,256,512)
    const int bb  = blockIdx.y;
    const int c   = ct0 + tid;

    const float w  = -__expf(w_log[c]);
    const float uu = u[c];

    // per-thread staging slice: 4 uint4 per array per chunk
    const int row0 = tid >> 5;           // 0..7 (row advances by 8 per j)
    const int col8 = tid & 31;           // uint4 index within a row

    uint4 kr[4], vr[4], rr[4];
    {   // prologue: issue chunk-0 loads
        const size_t gbase = ((size_t)bb * TT) * DD + ct0;
#pragma unroll
        for (int j = 0; j < 4; ++j) {
            const size_t a = gbase + (size_t)(row0 + j * 8) * DD + col8 * 8;
            kr[j] = *reinterpret_cast<const uint4*>(k + a);
            vr[j] = *reinterpret_cast<const uint4*>(v + a);
            rr[j] = *reinterpret_cast<const uint4*>(r + a);
        }
    }

    float aa = 0.f, bbv = 0.f, pp = -1e30f;

    for (int ci = 0; ci < NC; ++ci) {
        __syncthreads();   // previous chunk's compute done -> safe to overwrite
#pragma unroll
        for (int j = 0; j < 4; ++j) {
            const int rr0 = row0 + j * 8;
            *reinterpret_cast<uint4*>(&kb[rr0][col8 * 8]) = kr[j];
            *reinterpret_cast<uint4*>(&vb[rr0][col8 * 8]) = vr[j];
            *reinterpret_cast<uint4*>(&rb[rr0][col8 * 8]) = rr[j];
        }
        __syncthreads();   // LDS tile visible
        if (ci + 1 < NC) { // issue next chunk's loads (in flight during compute)
            const size_t gbase = ((size_t)bb * TT + (ci + 1) * CT) * DD + ct0;
#pragma unroll
            for (int j = 0; j < 4; ++j) {
                const size_t a = gbase + (size_t)(row0 + j * 8) * DD + col8 * 8;
                kr[j] = *reinterpret_cast<const uint4*>(k + a);
                vr[j] = *reinterpret_cast<const uint4*>(v + a);
                rr[j] = *reinterpret_cast<const uint4*>(r + a);
            }
        }
        __hip_bfloat16* op = rw + ((size_t)bb * TT + ci * CT) * DD + c;
#pragma unroll
        for (int t = 0; t < CT; ++t) {
            const float kt = bf2f(__hip_bfloat16_raw{kb[t][tid]});
            const float vt = bf2f(__hip_bfloat16_raw{vb[t][tid]});
            const float rt = bf2f(__hip_bfloat16_raw{rb[t][tid]});
            const float ww = uu + kt;
            const float p  = fmaxf(pp, ww);
            const float e1 = __expf(pp - p);
            const float e2 = __expf(ww - p);
            const float o  = (e1 * aa + e2 * vt) / (e1 * bbv + e2);
            op[(size_t)t * DD] = f2bf(rt * o);
            const float ww2 = pp + w;
            const float p2  = fmaxf(ww2, kt);
            const float e1b = __expf(ww2 - p2);
            const float e2b = __expf(kt - p2);
            aa  = e1b * aa + e2b * vt;
            bbv = e1b * bbv + e2b;
            pp  = p2;
        }
    }
}

// ---------------------------------------------------------------------------
extern "C" void kernel_launch(void* const* d_in, const int* in_sizes, int n_in,
                              void* d_out, int out_size, void* d_ws, size_t ws_size,
                              hipStream_t stream)
{
    (void)in_sizes; (void)n_in; (void)out_size;
    const float* x     = (const float*)d_in[0];
    // d_in[1]=H, d_in[2]=W (compile-time constants 32x32)
    const float* ln1_g = (const float*)d_in[3];
    const float* ln1_b = (const float*)d_in[4];
    const float* ln2_g = (const float*)d_in[5];
    const float* ln2_b = (const float*)d_in[6];
    const float* mu_k  = (const float*)d_in[7];
    const float* mu_v  = (const float*)d_in[8];
    const float* mu_r  = (const float*)d_in[9];
    const float* w_log = (const float*)d_in[10];
    const float* u     = (const float*)d_in[11];
    const float* Wk    = (const float*)d_in[12];
    const float* Wv    = (const float*)d_in[13];
    const float* Wr    = (const float*)d_in[14];
    const float* Wo    = (const float*)d_in[15];
    const float* cmu_k = (const float*)d_in[16];
    const float* cmu_r = (const float*)d_in[17];
    const float* Ck    = (const float*)d_in[18];
    const float* Cv    = (const float*)d_in[19];
    const float* Cr    = (const float*)d_in[20];
    float* out = (float*)d_out;

    // ---- workspace: 5 bf16 ND slots + bf16 weights + stats = 141.3 MB ----
    // slot timeline:
    //   S0: xk -> r   -> xk2
    //   S1: xv -> rw  -> cr
    //   S2: xr -> h
    //   S3: k  -> xr2 -> kk[lo]   (kk = 16384x1536 bf16 spans S3+S4, 2x SL)
    //   S4: v  ->        kk[hi]
    const size_t ND = (size_t)NROWS * DD;   // 12,582,912 elements
    const size_t SL = ND * 2;               // 25,165,824 B per bf16 slot
    const size_t WBYTES = (size_t)(5 * DW + 2 * DH) * 2;  // 15,335,424
    const size_t NEED = 5 * SL + WBYTES + 2 * (size_t)NROWS * sizeof(float);
    if (ws_size < NEED) return;  // diagnostic: absmax-fail instead of fault

    char* w = (char*)d_ws;
    __hip_bfloat16* S0 = (__hip_bfloat16*)(w);
    __hip_bfloat16* S1 = (__hip_bfloat16*)(w + 1 * SL);
    __hip_bfloat16* S2 = (__hip_bfloat16*)(w + 2 * SL);
    __hip_bfloat16* S3 = (__hip_bfloat16*)(w + 3 * SL);
    __hip_bfloat16* S4 = (__hip_bfloat16*)(w + 4 * SL);
    __hip_bfloat16* WkB = (__hip_bfloat16*)(w + 5 * SL);
    __hip_bfloat16* WvB = WkB + DW;
    __hip_bfloat16* WrB = WvB + DW;
    __hip_bfloat16* WoB = WrB + DW;
    __hip_bfloat16* CrB = WoB + DW;
    __hip_bfloat16* CkB = CrB + DW;
    __hip_bfloat16* CvB = CkB + DH;
    float* meanB = (float*)(w + 5 * SL + WBYTES);
    float* rstdB = meanB + NROWS;

    const int EW_GRID = (int)(ND / 256);      // 49152
    const dim3 g768(NROWS / BM, DD / BN);     // (128, 6)
    const dim3 g1536(NROWS / BM, HHALF / BN); // (128, 12)
    const int CB_W = DW / 4 / 256;            // 576
    const int CB_H = DH / 4 / 256;            // 2304

    // ---- weight conversion ----
    cvt_k<<<CB_W, 256, 0, stream>>>(Wk, WkB, DW);
    cvt_k<<<CB_W, 256, 0, stream>>>(Wv, WvB, DW);
    cvt_k<<<CB_W, 256, 0, stream>>>(Wr, WrB, DW);
    cvt_k<<<CB_W, 256, 0, stream>>>(Wo, WoB, DW);
    cvt_k<<<CB_W, 256, 0, stream>>>(Cr, CrB, DW);
    cvt_k<<<CB_H, 256, 0, stream>>>(Ck, CkB, DH);
    cvt_k<<<CB_H, 256, 0, stream>>>(Cv, CvB, DH);

    // ---- spatial mix ----
    ln_stats_k<float><<<NROWS, 256, 0, stream>>>(x, meanB, rstdB);
    mix_k<float, 3><<<EW_GRID, 256, 0, stream>>>(x, meanB, rstdB, ln1_g, ln1_b,
                                                 mu_k, mu_v, mu_r, S0, S1, S2);
    gemm_bt<0><<<g768, 256, 0, stream>>>(S0, WkB, DD, DD, DD, S3, nullptr, nullptr, nullptr, nullptr); // k
    gemm_bt<0><<<g768, 256, 0, stream>>>(S1, WvB, DD, DD, DD, S4, nullptr, nullptr, nullptr, nullptr); // v
    gemm_bt<1><<<g768, 256, 0, stream>>>(S2, WrB, DD, DD, DD, S0, nullptr, nullptr, nullptr, nullptr); // r=sigmoid
    wkv_lds_k<<<dim3(DD / CTILE, BBATCH), 256, 0, stream>>>(w_log, u, S3, S4, S0, S1);                 // rw
    gemm_bt<2><<<g768, 256, 0, stream>>>(S1, WoB, DD, DD, DD, S2, nullptr, nullptr, nullptr, x);       // h = acc + x

    // ---- channel mix ----
    ln_stats_k<__hip_bfloat16><<<NROWS, 256, 0, stream>>>(S2, meanB, rstdB);
    mix_k<__hip_bfloat16, 2><<<EW_GRID, 256, 0, stream>>>(S2, meanB, rstdB, ln2_g, ln2_b,
                                                          cmu_k, nullptr, cmu_r, S0, nullptr, S3);
    gemm_bt<1><<<g768, 256, 0, stream>>>(S3, CrB, DD, DD, DD, S1, nullptr, nullptr, nullptr, nullptr); // cr=sigmoid
    // FFN in two 1536-wide halves; kk lives in S3+S4 (contiguous)
    __hip_bfloat16* kk = S3;
    gemm_bt<3><<<g1536, 256, 0, stream>>>(S0, CkB, DD, DD, HHALF,
                                          kk, nullptr, nullptr, nullptr, nullptr);
    gemm_bt<4><<<g768, 256, 0, stream>>>(kk, CvB, HHALF, HIDN, DD,
                                         nullptr, out, S1, S2, x);
    gemm_bt<3><<<g1536, 256, 0, stream>>>(S0, CkB + (size_t)HHALF * DD, DD, DD, HHALF,
                                          kk, nullptr, nullptr, nullptr, nullptr);
    gemm_bt<5><<<g768, 256, 0, stream>>>(kk, CvB + HHALF, HHALF, HIDN, DD,
                                         nullptr, out, S1, nullptr, nullptr);
}

// Round 5
// 627.504 us; speedup vs baseline: 1.3638x; 1.2727x over previous
//
#include <hip/hip_runtime.h>
#include <hip/hip_bf16.h>

// Problem constants (fixed by the reference)
#define DD   768
#define TT   1024
#define BBATCH 16
#define NROWS (BBATCH * TT)   // 16384
#define HIDN 3072
#define HHALF 1536
#define HH 32
#define WW 32
#define DW  (DD * DD)         // 589824
#define DH  (DD * HIDN)       // 2359296
#define CCH 64                // wkv chunk length
#define PCH (TT / CCH)        // 16 chunks

typedef float  floatx4 __attribute__((ext_vector_type(4)));
typedef __bf16 bf16x8  __attribute__((ext_vector_type(8)));

__device__ __forceinline__ float bf2f(__hip_bfloat16 v) { return __bfloat162float(v); }
__device__ __forceinline__ __hip_bfloat16 f2bf(float v) { return __float2bfloat16(v); }
__device__ __forceinline__ float toF(__hip_bfloat16 v) { return __bfloat162float(v); }
__device__ __forceinline__ float toF(float v) { return v; }

// ---------------------------------------------------------------------------
// fp32 -> bf16 weight conversion (per-launch; d_ws is re-poisoned every call)
// ---------------------------------------------------------------------------
__global__ __launch_bounds__(256)
void cvt_k(const float* __restrict__ s, __hip_bfloat16* __restrict__ d, int n)
{
    const int i = (blockIdx.x * 256 + threadIdx.x) * 4;
    if (i >= n) return;
    const float4 v = *reinterpret_cast<const float4*>(s + i);
    __hip_bfloat16 o[4] = {f2bf(v.x), f2bf(v.y), f2bf(v.z), f2bf(v.w)};
    *reinterpret_cast<ushort4*>(d + i) = *reinterpret_cast<const ushort4*>(o);
}

// ---------------------------------------------------------------------------
// Per-row LN stats: mean + rstd (768 cols, 256 threads x 3)
// ---------------------------------------------------------------------------
template <typename TIN>
__global__ __launch_bounds__(256)
void ln_stats_k(const TIN* __restrict__ x,
                float* __restrict__ mean, float* __restrict__ rstd)
{
    const int row = blockIdx.x, tid = threadIdx.x;
    const int lane = tid & 63, wid = tid >> 6;
    const TIN* xr = x + (size_t)row * DD;
    float s1 = 0.f, s2 = 0.f;
#pragma unroll
    for (int i = 0; i < 3; ++i) {
        const float v = toF(xr[tid + i * 256]);
        s1 += v; s2 += v * v;
    }
#pragma unroll
    for (int off = 32; off > 0; off >>= 1) {
        s1 += __shfl_down(s1, off);
        s2 += __shfl_down(s2, off);
    }
    __shared__ float sh[8];
    if (lane == 0) { sh[wid] = s1; sh[4 + wid] = s2; }
    __syncthreads();
    if (tid == 0) {
        s1 = sh[0] + sh[1] + sh[2] + sh[3];
        s2 = sh[4] + sh[5] + sh[6] + sh[7];
        const float m = s1 * (1.f / DD);
        mean[row] = m;
        rstd[row] = rsqrtf(s2 * (1.f / DD) - m * m + 1e-5f);
    }
}

// ---------------------------------------------------------------------------
// LN-on-the-fly + q_shift + token-mix, bf16 outputs (GEMM A operands)
// ---------------------------------------------------------------------------
template <typename TIN>
__device__ __forceinline__ float ln_at(const TIN* __restrict__ x,
                                       const float* __restrict__ mean,
                                       const float* __restrict__ rstd,
                                       const float* __restrict__ g,
                                       const float* __restrict__ b,
                                       int grow, int c)
{
    return (toF(x[(size_t)grow * DD + c]) - mean[grow]) * rstd[grow] * g[c] + b[c];
}

template <typename TIN, int NOUT>
__global__ __launch_bounds__(256)
void mix_k(const TIN* __restrict__ x,
           const float* __restrict__ mean, const float* __restrict__ rstd,
           const float* __restrict__ g, const float* __restrict__ b,
           const float* __restrict__ muk,
           const float* __restrict__ muv,   // unused if NOUT==2
           const float* __restrict__ mur,
           __hip_bfloat16* __restrict__ xk,
           __hip_bfloat16* __restrict__ xv, // unused if NOUT==2
           __hip_bfloat16* __restrict__ xr)
{
    const size_t idx = (size_t)blockIdx.x * 256 + threadIdx.x;
    const int c  = (int)(idx % DD);
    const int n  = (int)((idx / DD) % TT);
    const int bb = (int)(idx / ((size_t)DD * TT));
    const int y = n >> 5, xp = n & 31;
    const int grow = bb * TT + n;

    const float av = ln_at(x, mean, rstd, g, b, grow, c);

    // quad-directional shift on the normalized tensor (zero-pad OOB)
    const int grp = c / (DD / 4);
    int ny = y, nx = xp; bool ok;
    if      (grp == 0) { nx = xp - 1; ok = xp > 0;      }
    else if (grp == 1) { nx = xp + 1; ok = xp < WW - 1; }
    else if (grp == 2) { ny = y - 1;  ok = y > 0;       }
    else               { ny = y + 1;  ok = y < HH - 1;  }
    const float sx = ok ? ln_at(x, mean, rstd, g, b, bb * TT + ny * WW + nx, c) : 0.f;

    const float mk = muk[c], mr = mur[c];
    xk[idx] = f2bf(av * mk + sx * (1.f - mk));
    xr[idx] = f2bf(av * mr + sx * (1.f - mr));
    if (NOUT == 3) {
        const float mv = muv[c];
        xv[idx] = f2bf(av * mv + sx * (1.f - mv));
    }
}

// ---------------------------------------------------------------------------
// GEMM: C[M, Nn] = A[M, K packed] @ W[Nn rows, stride Wstr]^T, bf16 in,
// fp32 accum. 128x128 tile, 4 waves (2x2 of 64x64), BK=64,
// mfma_f32_16x16x32_bf16. LDS row stride 72 bf16 (144 B): 16B-aligned
// ds_read_b128, only 2-way bank alias (free per m136).
// MODE: 0=bf16(acc), 1=bf16(sigmoid), 2=bf16(acc + xf32), 3=bf16(relu^2),
//       4=f32 out = h + s*acc + x, 5=f32 out += s*acc
// ---------------------------------------------------------------------------
#define BM 128
#define BN 128
#define BKK 64
#define LSTR 72

template <int MODE>
__global__ __launch_bounds__(256, 2)
void gemm_bt(const __hip_bfloat16* __restrict__ A,
             const __hip_bfloat16* __restrict__ W,
             int K, int Wstr, int Nn,
             __hip_bfloat16* __restrict__ outB,
             float* __restrict__ outF,
             const __hip_bfloat16* __restrict__ auxS,  // sigmoid gate [4,5]
             const __hip_bfloat16* __restrict__ auxH,  // h bf16       [4]
             const float* __restrict__ auxX)           // x fp32       [2,4]
{
    __shared__ __align__(16) unsigned short lA[BM * LSTR];
    __shared__ __align__(16) unsigned short lB[BN * LSTR];

    const int tid  = threadIdx.x;
    const int bm   = blockIdx.x, bn = blockIdx.y;
    const int lane = tid & 63, wid = tid >> 6;
    const int l15  = lane & 15, quad = lane >> 4;
    const int m0   = (wid & 1) * 64;
    const int n0   = (wid >> 1) * 64;

    floatx4 acc[4][4];
#pragma unroll
    for (int i = 0; i < 4; ++i)
#pragma unroll
        for (int j = 0; j < 4; ++j)
            acc[i][j] = floatx4{0.f, 0.f, 0.f, 0.f};

    for (int k0 = 0; k0 < K; k0 += BKK) {
#pragma unroll
        for (int it = 0; it < 4; ++it) {
            const int chunk = tid + it * 256;   // 0..1023
            const int r  = chunk >> 3;          // 0..127
            const int c8 = chunk & 7;           // 8 bf16 each
            const uint4 va = *reinterpret_cast<const uint4*>(
                A + (size_t)(bm * BM + r) * K + k0 + c8 * 8);
            const uint4 vb = *reinterpret_cast<const uint4*>(
                W + (size_t)(bn * BN + r) * Wstr + k0 + c8 * 8);
            *reinterpret_cast<uint4*>(&lA[r * LSTR + c8 * 8]) = va;
            *reinterpret_cast<uint4*>(&lB[r * LSTR + c8 * 8]) = vb;
        }
        __syncthreads();
#pragma unroll
        for (int kk = 0; kk < BKK; kk += 32) {
            bf16x8 af[4], bfr[4];
#pragma unroll
            for (int i = 0; i < 4; ++i)
                af[i] = *reinterpret_cast<const bf16x8*>(
                    &lA[(m0 + i * 16 + l15) * LSTR + kk + quad * 8]);
#pragma unroll
            for (int j = 0; j < 4; ++j)
                bfr[j] = *reinterpret_cast<const bf16x8*>(
                    &lB[(n0 + j * 16 + l15) * LSTR + kk + quad * 8]);
#pragma unroll
            for (int i = 0; i < 4; ++i)
#pragma unroll
                for (int j = 0; j < 4; ++j)
                    acc[i][j] = __builtin_amdgcn_mfma_f32_16x16x32_bf16(
                        af[i], bfr[j], acc[i][j], 0, 0, 0);
        }
        __syncthreads();
    }

    // Epilogue. C/D layout: col = lane&15, row = quad*4 + reg  [m89/m91]
#pragma unroll
    for (int i = 0; i < 4; ++i) {
#pragma unroll
        for (int j = 0; j < 4; ++j) {
#pragma unroll
            for (int r = 0; r < 4; ++r) {
                const int grow = bm * BM + m0 + i * 16 + quad * 4 + r;
                const int gcol = bn * BN + n0 + j * 16 + l15;
                const size_t idx = (size_t)grow * Nn + gcol;
                const float v = acc[i][j][r];
                if (MODE == 0) {
                    outB[idx] = f2bf(v);
                } else if (MODE == 1) {
                    outB[idx] = f2bf(1.f / (1.f + __expf(-v)));
                } else if (MODE == 2) {
                    outB[idx] = f2bf(v + auxX[idx]);
                } else if (MODE == 3) {
                    const float t = fmaxf(v, 0.f);
                    outB[idx] = f2bf(t * t);
                } else if (MODE == 4) {
                    outF[idx] = bf2f(auxH[idx]) + bf2f(auxS[idx]) * v + auxX[idx];
                } else {
                    outF[idx] += bf2f(auxS[idx]) * v;
                }
            }
        }
    }
}

// ---------------------------------------------------------------------------
// WKV parallel scan over T. Recurrence is associative: with A=aa*e^pp,
// B=bb*e^pp it is A' = e^w * A + e^{k_t} * v_t. Split T into PCH chunks of
// CCH; pass A computes chunk summaries from zero state, a small kernel does
// the stabilized exclusive combine across chunks, pass B replays each chunk
// from its prefix emitting r-gated outputs (per-step formulas identical to
// the reference). Parallelism: 192 waves -> 3072 waves.
// ---------------------------------------------------------------------------
__global__ __launch_bounds__(256)
void wkv_passA(const float* __restrict__ w_log,
               const __hip_bfloat16* __restrict__ k,
               const __hip_bfloat16* __restrict__ v,
               float* __restrict__ SA, float* __restrict__ SB,
               float* __restrict__ SP)
{
    const int c  = blockIdx.x * 256 + threadIdx.x;  // 0..767
    const int j  = blockIdx.y;                      // chunk
    const int bb = blockIdx.z;                      // batch
    const float w = -__expf(w_log[c]);
    const size_t base = ((size_t)bb * TT + j * CCH) * DD + c;
    float a = 0.f, b = 0.f, p = -1e30f;
#pragma unroll 4
    for (int t = 0; t < CCH; ++t) {
        const size_t o = base + (size_t)t * DD;
        const float kt = bf2f(k[o]);
        const float vt = bf2f(v[o]);
        const float ww2 = p + w;
        const float p2  = fmaxf(ww2, kt);
        const float e1  = __expf(ww2 - p2);
        const float e2  = __expf(kt - p2);
        a = e1 * a + e2 * vt;
        b = e1 * b + e2;
        p = p2;
    }
    const size_t si = ((size_t)bb * PCH + j) * DD + c;
    SA[si] = a; SB[si] = b; SP[si] = p;
}

__global__ __launch_bounds__(256)
void wkv_scanj(const float* __restrict__ w_log,
               float* __restrict__ SA, float* __restrict__ SB,
               float* __restrict__ SP)
{
    const int idx = blockIdx.x * 256 + threadIdx.x;  // 0..B*D-1
    const int c = idx % DD, bb = idx / DD;
    const float wC = -__expf(w_log[c]) * (float)CCH;  // decay over one chunk
    float a = 0.f, b = 0.f, p = -1e30f;
#pragma unroll
    for (int j = 0; j < PCH; ++j) {
        const size_t si = ((size_t)bb * PCH + j) * DD + c;
        const float aj = SA[si], bj = SB[si], pj = SP[si];
        SA[si] = a; SB[si] = b; SP[si] = p;   // exclusive prefix (chunk input)
        const float pd = p + wC;
        const float pn = fmaxf(pd, pj);
        const float e1 = __expf(pd - pn);
        const float e2 = __expf(pj - pn);
        a = e1 * a + e2 * aj;
        b = e1 * b + e2 * bj;
        p = pn;
    }
}

__global__ __launch_bounds__(256)
void wkv_passB(const float* __restrict__ w_log, const float* __restrict__ u,
               const __hip_bfloat16* __restrict__ k,
               const __hip_bfloat16* __restrict__ v,
               const __hip_bfloat16* __restrict__ r,
               __hip_bfloat16* __restrict__ rw,
               const float* __restrict__ SA, const float* __restrict__ SB,
               const float* __restrict__ SP)
{
    const int c  = blockIdx.x * 256 + threadIdx.x;
    const int j  = blockIdx.y;
    const int bb = blockIdx.z;
    const float w  = -__expf(w_log[c]);
    const float uu = u[c];
    const size_t si = ((size_t)bb * PCH + j) * DD + c;
    float aa = SA[si], bbv = SB[si], pp = SP[si];
    const size_t base = ((size_t)bb * TT + j * CCH) * DD + c;
#pragma unroll 4
    for (int t = 0; t < CCH; ++t) {
        const size_t o = base + (size_t)t * DD;
        const float kt = bf2f(k[o]);
        const float vt = bf2f(v[o]);
        const float rt = bf2f(r[o]);
        const float ww = uu + kt;
        const float p  = fmaxf(pp, ww);
        const float e1 = __expf(pp - p);
        const float e2 = __expf(ww - p);
        const float ov = __fdividef(e1 * aa + e2 * vt, e1 * bbv + e2);
        rw[o] = f2bf(rt * ov);
        const float ww2 = pp + w;
        const float p2  = fmaxf(ww2, kt);
        const float e1b = __expf(ww2 - p2);
        const float e2b = __expf(kt - p2);
        aa  = e1b * aa + e2b * vt;
        bbv = e1b * bbv + e2b;
        pp  = p2;
    }
}

// ---------------------------------------------------------------------------
extern "C" void kernel_launch(void* const* d_in, const int* in_sizes, int n_in,
                              void* d_out, int out_size, void* d_ws, size_t ws_size,
                              hipStream_t stream)
{
    (void)in_sizes; (void)n_in; (void)out_size;
    const float* x     = (const float*)d_in[0];
    // d_in[1]=H, d_in[2]=W (compile-time constants 32x32)
    const float* ln1_g = (const float*)d_in[3];
    const float* ln1_b = (const float*)d_in[4];
    const float* ln2_g = (const float*)d_in[5];
    const float* ln2_b = (const float*)d_in[6];
    const float* mu_k  = (const float*)d_in[7];
    const float* mu_v  = (const float*)d_in[8];
    const float* mu_r  = (const float*)d_in[9];
    const float* w_log = (const float*)d_in[10];
    const float* u     = (const float*)d_in[11];
    const float* Wk    = (const float*)d_in[12];
    const float* Wv    = (const float*)d_in[13];
    const float* Wr    = (const float*)d_in[14];
    const float* Wo    = (const float*)d_in[15];
    const float* cmu_k = (const float*)d_in[16];
    const float* cmu_r = (const float*)d_in[17];
    const float* Ck    = (const float*)d_in[18];
    const float* Cv    = (const float*)d_in[19];
    const float* Cr    = (const float*)d_in[20];
    float* out = (float*)d_out;

    // ---- workspace: 5 bf16 ND slots + bf16 weights + stats + scan states
    // slot timeline:
    //   S0: xk -> r   -> xk2
    //   S1: xv -> rw  -> cr
    //   S2: xr -> h
    //   S3: k  -> xr2 -> kk[lo]   (kk = 16384x1536 bf16 spans S3+S4, 2x SL)
    //   S4: v  ->        kk[hi]
    const size_t ND = (size_t)NROWS * DD;   // 12,582,912 elements
    const size_t SL = ND * 2;               // 25,165,824 B per bf16 slot
    const size_t WBYTES = (size_t)(5 * DW + 2 * DH) * 2;  // 15,335,424
    const size_t NSTATE = (size_t)BBATCH * PCH * DD;      // 196,608
    const size_t NEED = 5 * SL + WBYTES
                      + 2 * (size_t)NROWS * sizeof(float)
                      + 3 * NSTATE * sizeof(float);       // ~143.6 MB
    if (ws_size < NEED) return;  // diagnostic: absmax-fail instead of fault

    char* w = (char*)d_ws;
    __hip_bfloat16* S0 = (__hip_bfloat16*)(w);
    __hip_bfloat16* S1 = (__hip_bfloat16*)(w + 1 * SL);
    __hip_bfloat16* S2 = (__hip_bfloat16*)(w + 2 * SL);
    __hip_bfloat16* S3 = (__hip_bfloat16*)(w + 3 * SL);
    __hip_bfloat16* S4 = (__hip_bfloat16*)(w + 4 * SL);
    __hip_bfloat16* WkB = (__hip_bfloat16*)(w + 5 * SL);
    __hip_bfloat16* WvB = WkB + DW;
    __hip_bfloat16* WrB = WvB + DW;
    __hip_bfloat16* WoB = WrB + DW;
    __hip_bfloat16* CrB = WoB + DW;
    __hip_bfloat16* CkB = CrB + DW;
    __hip_bfloat16* CvB = CkB + DH;
    float* meanB = (float*)(w + 5 * SL + WBYTES);
    float* rstdB = meanB + NROWS;
    float* SAb = rstdB + NROWS;
    float* SBb = SAb + NSTATE;
    float* SPb = SBb + NSTATE;

    const int EW_GRID = (int)(ND / 256);      // 49152
    const dim3 g768(NROWS / BM, DD / BN);     // (128, 6)
    const dim3 g1536(NROWS / BM, HHALF / BN); // (128, 12)
    const dim3 gwkv(DD / 256, PCH, BBATCH);   // (3, 16, 16)
    const int CB_W = DW / 4 / 256;            // 576
    const int CB_H = DH / 4 / 256;            // 2304

    // ---- weight conversion ----
    cvt_k<<<CB_W, 256, 0, stream>>>(Wk, WkB, DW);
    cvt_k<<<CB_W, 256, 0, stream>>>(Wv, WvB, DW);
    cvt_k<<<CB_W, 256, 0, stream>>>(Wr, WrB, DW);
    cvt_k<<<CB_W, 256, 0, stream>>>(Wo, WoB, DW);
    cvt_k<<<CB_W, 256, 0, stream>>>(Cr, CrB, DW);
    cvt_k<<<CB_H, 256, 0, stream>>>(Ck, CkB, DH);
    cvt_k<<<CB_H, 256, 0, stream>>>(Cv, CvB, DH);

    // ---- spatial mix ----
    ln_stats_k<float><<<NROWS, 256, 0, stream>>>(x, meanB, rstdB);
    mix_k<float, 3><<<EW_GRID, 256, 0, stream>>>(x, meanB, rstdB, ln1_g, ln1_b,
                                                 mu_k, mu_v, mu_r, S0, S1, S2);
    gemm_bt<0><<<g768, 256, 0, stream>>>(S0, WkB, DD, DD, DD, S3, nullptr, nullptr, nullptr, nullptr); // k
    gemm_bt<0><<<g768, 256, 0, stream>>>(S1, WvB, DD, DD, DD, S4, nullptr, nullptr, nullptr, nullptr); // v
    gemm_bt<1><<<g768, 256, 0, stream>>>(S2, WrB, DD, DD, DD, S0, nullptr, nullptr, nullptr, nullptr); // r=sigmoid
    wkv_passA<<<gwkv, 256, 0, stream>>>(w_log, S3, S4, SAb, SBb, SPb);
    wkv_scanj<<<(BBATCH * DD) / 256, 256, 0, stream>>>(w_log, SAb, SBb, SPb);
    wkv_passB<<<gwkv, 256, 0, stream>>>(w_log, u, S3, S4, S0, S1, SAb, SBb, SPb); // rw -> S1
    gemm_bt<2><<<g768, 256, 0, stream>>>(S1, WoB, DD, DD, DD, S2, nullptr, nullptr, nullptr, x);       // h = acc + x

    // ---- channel mix ----
    ln_stats_k<__hip_bfloat16><<<NROWS, 256, 0, stream>>>(S2, meanB, rstdB);
    mix_k<__hip_bfloat16, 2><<<EW_GRID, 256, 0, stream>>>(S2, meanB, rstdB, ln2_g, ln2_b,
                                                          cmu_k, nullptr, cmu_r, S0, nullptr, S3);
    gemm_bt<1><<<g768, 256, 0, stream>>>(S3, CrB, DD, DD, DD, S1, nullptr, nullptr, nullptr, nullptr); // cr=sigmoid
    // FFN in two 1536-wide halves; kk lives in S3+S4 (contiguous)
    __hip_bfloat16* kk = S3;
    gemm_bt<3><<<g1536, 256, 0, stream>>>(S0, CkB, DD, DD, HHALF,
                                          kk, nullptr, nullptr, nullptr, nullptr);
    gemm_bt<4><<<g768, 256, 0, stream>>>(kk, CvB, HHALF, HIDN, DD,
                                         nullptr, out, S1, S2, x);
    gemm_bt<3><<<g1536, 256, 0, stream>>>(S0, CkB + (size_t)HHALF * DD, DD, DD, HHALF,
                                          kk, nullptr, nullptr, nullptr, nullptr);
    gemm_bt<5><<<g768, 256, 0, stream>>>(kk, CvB + HHALF, HHALF, HIDN, DD,
                                         nullptr, out, S1, nullptr, nullptr);
}

// Round 6
// 614.773 us; speedup vs baseline: 1.3920x; 1.0207x over previous
//
#include <hip/hip_runtime.h>
#include <hip/hip_bf16.h>

// Problem constants (fixed by the reference)
#define DD   768
#define TT   1024
#define BBATCH 16
#define NROWS (BBATCH * TT)   // 16384
#define HIDN 3072
#define HHALF 1536
#define HH 32
#define WW 32
#define DW  (DD * DD)         // 589824
#define DH  (DD * HIDN)       // 2359296
#define CCH 64                // wkv chunk length
#define PCH (TT / CCH)        // 16 chunks

typedef float  floatx4 __attribute__((ext_vector_type(4)));
typedef __bf16 bf16x8  __attribute__((ext_vector_type(8)));

__device__ __forceinline__ float bf2f(__hip_bfloat16 v) { return __bfloat162float(v); }
__device__ __forceinline__ __hip_bfloat16 f2bf(float v) { return __float2bfloat16(v); }
__device__ __forceinline__ float toF(__hip_bfloat16 v) { return __bfloat162float(v); }
__device__ __forceinline__ float toF(float v) { return v; }

// global -> LDS direct DMA, 16 B per lane, dest = uniform base + lane*16
#define GL2LDS(gp, lp)  __builtin_amdgcn_global_load_lds(                     \
    (const __attribute__((address_space(1))) void*)(gp),                      \
    (__attribute__((address_space(3))) void*)(lp), 16, 0, 0)

// ---------------------------------------------------------------------------
// fp32 -> bf16 weight conversion (per-launch; d_ws is re-poisoned every call)
// ---------------------------------------------------------------------------
__global__ __launch_bounds__(256)
void cvt_k(const float* __restrict__ s, __hip_bfloat16* __restrict__ d, int n)
{
    const int i = (blockIdx.x * 256 + threadIdx.x) * 4;
    if (i >= n) return;
    const float4 v = *reinterpret_cast<const float4*>(s + i);
    __hip_bfloat16 o[4] = {f2bf(v.x), f2bf(v.y), f2bf(v.z), f2bf(v.w)};
    *reinterpret_cast<ushort4*>(d + i) = *reinterpret_cast<const ushort4*>(o);
}

// ---------------------------------------------------------------------------
// Per-row LN stats: mean + rstd (768 cols, 256 threads x 3)
// ---------------------------------------------------------------------------
template <typename TIN>
__global__ __launch_bounds__(256)
void ln_stats_k(const TIN* __restrict__ x,
                float* __restrict__ mean, float* __restrict__ rstd)
{
    const int row = blockIdx.x, tid = threadIdx.x;
    const int lane = tid & 63, wid = tid >> 6;
    const TIN* xr = x + (size_t)row * DD;
    float s1 = 0.f, s2 = 0.f;
#pragma unroll
    for (int i = 0; i < 3; ++i) {
        const float v = toF(xr[tid + i * 256]);
        s1 += v; s2 += v * v;
    }
#pragma unroll
    for (int off = 32; off > 0; off >>= 1) {
        s1 += __shfl_down(s1, off);
        s2 += __shfl_down(s2, off);
    }
    __shared__ float sh[8];
    if (lane == 0) { sh[wid] = s1; sh[4 + wid] = s2; }
    __syncthreads();
    if (tid == 0) {
        s1 = sh[0] + sh[1] + sh[2] + sh[3];
        s2 = sh[4] + sh[5] + sh[6] + sh[7];
        const float m = s1 * (1.f / DD);
        mean[row] = m;
        rstd[row] = rsqrtf(s2 * (1.f / DD) - m * m + 1e-5f);
    }
}

// ---------------------------------------------------------------------------
// LN-on-the-fly + q_shift + token-mix, bf16 outputs (GEMM A operands)
// ---------------------------------------------------------------------------
template <typename TIN>
__device__ __forceinline__ float ln_at(const TIN* __restrict__ x,
                                       const float* __restrict__ mean,
                                       const float* __restrict__ rstd,
                                       const float* __restrict__ g,
                                       const float* __restrict__ b,
                                       int grow, int c)
{
    return (toF(x[(size_t)grow * DD + c]) - mean[grow]) * rstd[grow] * g[c] + b[c];
}

template <typename TIN, int NOUT>
__global__ __launch_bounds__(256)
void mix_k(const TIN* __restrict__ x,
           const float* __restrict__ mean, const float* __restrict__ rstd,
           const float* __restrict__ g, const float* __restrict__ b,
           const float* __restrict__ muk,
           const float* __restrict__ muv,   // unused if NOUT==2
           const float* __restrict__ mur,
           __hip_bfloat16* __restrict__ xk,
           __hip_bfloat16* __restrict__ xv, // unused if NOUT==2
           __hip_bfloat16* __restrict__ xr)
{
    const size_t idx = (size_t)blockIdx.x * 256 + threadIdx.x;
    const int c  = (int)(idx % DD);
    const int n  = (int)((idx / DD) % TT);
    const int bb = (int)(idx / ((size_t)DD * TT));
    const int y = n >> 5, xp = n & 31;
    const int grow = bb * TT + n;

    const float av = ln_at(x, mean, rstd, g, b, grow, c);

    // quad-directional shift on the normalized tensor (zero-pad OOB)
    const int grp = c / (DD / 4);
    int ny = y, nx = xp; bool ok;
    if      (grp == 0) { nx = xp - 1; ok = xp > 0;      }
    else if (grp == 1) { nx = xp + 1; ok = xp < WW - 1; }
    else if (grp == 2) { ny = y - 1;  ok = y > 0;       }
    else               { ny = y + 1;  ok = y < HH - 1;  }
    const float sx = ok ? ln_at(x, mean, rstd, g, b, bb * TT + ny * WW + nx, c) : 0.f;

    const float mk = muk[c], mr = mur[c];
    xk[idx] = f2bf(av * mk + sx * (1.f - mk));
    xr[idx] = f2bf(av * mr + sx * (1.f - mr));
    if (NOUT == 3) {
        const float mv = muv[c];
        xv[idx] = f2bf(av * mv + sx * (1.f - mv));
    }
}

// ---------------------------------------------------------------------------
// GEMM: C[M, Nn] = A[M, K packed] @ W[Nn rows, stride Wstr]^T, bf16 in,
// fp32 accum. 128x128 tile, 4 waves (2x2 of 64x64), BK=64,
// mfma_f32_16x16x32_bf16.
// Staging: __builtin_amdgcn_global_load_lds width=16 (m97 pattern, 517->874
// TF on the ladder). LDS dest constraint = uniform base + lane*16 forbids
// padding, so rows are unpadded (128 B) with XOR col-group swizzle:
// element (row, g) lives at col-group g^(row&7). Write side: lane i of an
// 8-row segment fetches colgroup (i&7)^((i>>3)&7) -> lands at slot i&7.
// Read side: 16 l15-lanes hit 8 distinct bank-starts x 2-way = free (m136).
// MODE: 0=bf16(acc), 1=bf16(sigmoid), 2=bf16(acc + xf32), 3=bf16(relu^2),
//       4=f32 out = h + s*acc + x, 5=f32 out += s*acc
// ---------------------------------------------------------------------------
#define BM 128
#define BN 128
#define BKK 64

template <int MODE>
__global__ __launch_bounds__(256, 2)
void gemm_bt(const __hip_bfloat16* __restrict__ A,
             const __hip_bfloat16* __restrict__ W,
             int K, int Wstr, int Nn,
             __hip_bfloat16* __restrict__ outB,
             float* __restrict__ outF,
             const __hip_bfloat16* __restrict__ auxS,  // sigmoid gate [4,5]
             const __hip_bfloat16* __restrict__ auxH,  // h bf16       [4]
             const float* __restrict__ auxX)           // x fp32       [2,4]
{
    __shared__ __align__(16) unsigned short lA[BM * BKK];  // 16 KB
    __shared__ __align__(16) unsigned short lB[BN * BKK];  // 16 KB

    const int tid  = threadIdx.x;
    const int bm   = blockIdx.x, bn = blockIdx.y;
    const int lane = tid & 63, wid = tid >> 6;
    const int l15  = lane & 15, quad = lane >> 4;
    const int m0   = (wid & 1) * 64;
    const int n0   = (wid >> 1) * 64;

    // staging geometry: per-wave 4 segments of 8 rows; lane -> (row, colgroup)
    const int srow  = lane >> 3;                 // 0..7 row within segment
    const int gcolg = (lane & 7) ^ (srow & 7);   // swizzled col-group to fetch
    const int s0    = wid * 4;                   // first segment of this wave

    floatx4 acc[4][4];
#pragma unroll
    for (int i = 0; i < 4; ++i)
#pragma unroll
        for (int j = 0; j < 4; ++j)
            acc[i][j] = floatx4{0.f, 0.f, 0.f, 0.f};

    const int swzbase = l15 & 7;   // row&7 for all fragment rows this lane

    for (int k0 = 0; k0 < K; k0 += BKK) {
#pragma unroll
        for (int t = 0; t < 4; ++t) {
            const int s   = s0 + t;
            const int row = s * 8 + srow;
            GL2LDS(A + (size_t)(bm * BM + row) * K    + k0 + gcolg * 8,
                   &lA[s * 512]);
            GL2LDS(W + (size_t)(bn * BN + row) * Wstr + k0 + gcolg * 8,
                   &lB[s * 512]);
        }
        __syncthreads();   // drains vmcnt -> tiles resident
#pragma unroll
        for (int kk = 0; kk < BKK; kk += 32) {
            const int swz = (((kk >> 3) + quad) ^ swzbase) * 8;
            bf16x8 af[4], bfr[4];
#pragma unroll
            for (int i = 0; i < 4; ++i)
                af[i] = *reinterpret_cast<const bf16x8*>(
                    &lA[(m0 + i * 16 + l15) * BKK + swz]);
#pragma unroll
            for (int j = 0; j < 4; ++j)
                bfr[j] = *reinterpret_cast<const bf16x8*>(
                    &lB[(n0 + j * 16 + l15) * BKK + swz]);
#pragma unroll
            for (int i = 0; i < 4; ++i)
#pragma unroll
                for (int j = 0; j < 4; ++j)
                    acc[i][j] = __builtin_amdgcn_mfma_f32_16x16x32_bf16(
                        af[i], bfr[j], acc[i][j], 0, 0, 0);
        }
        __syncthreads();   // compute done -> safe to overwrite tiles
    }

    // Epilogue. C/D layout: col = lane&15, row = quad*4 + reg  [m89/m91]
#pragma unroll
    for (int i = 0; i < 4; ++i) {
#pragma unroll
        for (int j = 0; j < 4; ++j) {
#pragma unroll
            for (int r = 0; r < 4; ++r) {
                const int grow = bm * BM + m0 + i * 16 + quad * 4 + r;
                const int gcol = bn * BN + n0 + j * 16 + l15;
                const size_t idx = (size_t)grow * Nn + gcol;
                const float v = acc[i][j][r];
                if (MODE == 0) {
                    outB[idx] = f2bf(v);
                } else if (MODE == 1) {
                    outB[idx] = f2bf(1.f / (1.f + __expf(-v)));
                } else if (MODE == 2) {
                    outB[idx] = f2bf(v + auxX[idx]);
                } else if (MODE == 3) {
                    const float t = fmaxf(v, 0.f);
                    outB[idx] = f2bf(t * t);
                } else if (MODE == 4) {
                    outF[idx] = bf2f(auxH[idx]) + bf2f(auxS[idx]) * v + auxX[idx];
                } else {
                    outF[idx] += bf2f(auxS[idx]) * v;
                }
            }
        }
    }
}

// ---------------------------------------------------------------------------
// WKV parallel scan over T (chunked two-pass; round-5 verified).
// ---------------------------------------------------------------------------
__global__ __launch_bounds__(256)
void wkv_passA(const float* __restrict__ w_log,
               const __hip_bfloat16* __restrict__ k,
               const __hip_bfloat16* __restrict__ v,
               float* __restrict__ SA, float* __restrict__ SB,
               float* __restrict__ SP)
{
    const int c  = blockIdx.x * 256 + threadIdx.x;  // 0..767
    const int j  = blockIdx.y;                      // chunk
    const int bb = blockIdx.z;                      // batch
    const float w = -__expf(w_log[c]);
    const size_t base = ((size_t)bb * TT + j * CCH) * DD + c;
    float a = 0.f, b = 0.f, p = -1e30f;
#pragma unroll 4
    for (int t = 0; t < CCH; ++t) {
        const size_t o = base + (size_t)t * DD;
        const float kt = bf2f(k[o]);
        const float vt = bf2f(v[o]);
        const float ww2 = p + w;
        const float p2  = fmaxf(ww2, kt);
        const float e1  = __expf(ww2 - p2);
        const float e2  = __expf(kt - p2);
        a = e1 * a + e2 * vt;
        b = e1 * b + e2;
        p = p2;
    }
    const size_t si = ((size_t)bb * PCH + j) * DD + c;
    SA[si] = a; SB[si] = b; SP[si] = p;
}

__global__ __launch_bounds__(256)
void wkv_scanj(const float* __restrict__ w_log,
               float* __restrict__ SA, float* __restrict__ SB,
               float* __restrict__ SP)
{
    const int idx = blockIdx.x * 256 + threadIdx.x;  // 0..B*D-1
    const int c = idx % DD, bb = idx / DD;
    const float wC = -__expf(w_log[c]) * (float)CCH;  // decay over one chunk
    float a = 0.f, b = 0.f, p = -1e30f;
#pragma unroll
    for (int j = 0; j < PCH; ++j) {
        const size_t si = ((size_t)bb * PCH + j) * DD + c;
        const float aj = SA[si], bj = SB[si], pj = SP[si];
        SA[si] = a; SB[si] = b; SP[si] = p;   // exclusive prefix (chunk input)
        const float pd = p + wC;
        const float pn = fmaxf(pd, pj);
        const float e1 = __expf(pd - pn);
        const float e2 = __expf(pj - pn);
        a = e1 * a + e2 * aj;
        b = e1 * b + e2 * bj;
        p = pn;
    }
}

__global__ __launch_bounds__(256)
void wkv_passB(const float* __restrict__ w_log, const float* __restrict__ u,
               const __hip_bfloat16* __restrict__ k,
               const __hip_bfloat16* __restrict__ v,
               const __hip_bfloat16* __restrict__ r,
               __hip_bfloat16* __restrict__ rw,
               const float* __restrict__ SA, const float* __restrict__ SB,
               const float* __restrict__ SP)
{
    const int c  = blockIdx.x * 256 + threadIdx.x;
    const int j  = blockIdx.y;
    const int bb = blockIdx.z;
    const float w  = -__expf(w_log[c]);
    const float uu = u[c];
    const size_t si = ((size_t)bb * PCH + j) * DD + c;
    float aa = SA[si], bbv = SB[si], pp = SP[si];
    const size_t base = ((size_t)bb * TT + j * CCH) * DD + c;
#pragma unroll 4
    for (int t = 0; t < CCH; ++t) {
        const size_t o = base + (size_t)t * DD;
        const float kt = bf2f(k[o]);
        const float vt = bf2f(v[o]);
        const float rt = bf2f(r[o]);
        const float ww = uu + kt;
        const float p  = fmaxf(pp, ww);
        const float e1 = __expf(pp - p);
        const float e2 = __expf(ww - p);
        const float ov = __fdividef(e1 * aa + e2 * vt, e1 * bbv + e2);
        rw[o] = f2bf(rt * ov);
        const float ww2 = pp + w;
        const float p2  = fmaxf(ww2, kt);
        const float e1b = __expf(ww2 - p2);
        const float e2b = __expf(kt - p2);
        aa  = e1b * aa + e2b * vt;
        bbv = e1b * bbv + e2b;
        pp  = p2;
    }
}

// ---------------------------------------------------------------------------
extern "C" void kernel_launch(void* const* d_in, const int* in_sizes, int n_in,
                              void* d_out, int out_size, void* d_ws, size_t ws_size,
                              hipStream_t stream)
{
    (void)in_sizes; (void)n_in; (void)out_size;
    const float* x     = (const float*)d_in[0];
    // d_in[1]=H, d_in[2]=W (compile-time constants 32x32)
    const float* ln1_g = (const float*)d_in[3];
    const float* ln1_b = (const float*)d_in[4];
    const float* ln2_g = (const float*)d_in[5];
    const float* ln2_b = (const float*)d_in[6];
    const float* mu_k  = (const float*)d_in[7];
    const float* mu_v  = (const float*)d_in[8];
    const float* mu_r  = (const float*)d_in[9];
    const float* w_log = (const float*)d_in[10];
    const float* u     = (const float*)d_in[11];
    const float* Wk    = (const float*)d_in[12];
    const float* Wv    = (const float*)d_in[13];
    const float* Wr    = (const float*)d_in[14];
    const float* Wo    = (const float*)d_in[15];
    const float* cmu_k = (const float*)d_in[16];
    const float* cmu_r = (const float*)d_in[17];
    const float* Ck    = (const float*)d_in[18];
    const float* Cv    = (const float*)d_in[19];
    const float* Cr    = (const float*)d_in[20];
    float* out = (float*)d_out;

    // ---- workspace: 5 bf16 ND slots + bf16 weights + stats + scan states
    // slot timeline:
    //   S0: xk -> r   -> xk2
    //   S1: xv -> rw  -> cr
    //   S2: xr -> h
    //   S3: k  -> xr2 -> kk[lo]   (kk = 16384x1536 bf16 spans S3+S4, 2x SL)
    //   S4: v  ->        kk[hi]
    const size_t ND = (size_t)NROWS * DD;   // 12,582,912 elements
    const size_t SL = ND * 2;               // 25,165,824 B per bf16 slot
    const size_t WBYTES = (size_t)(5 * DW + 2 * DH) * 2;  // 15,335,424
    const size_t NSTATE = (size_t)BBATCH * PCH * DD;      // 196,608
    const size_t NEED = 5 * SL + WBYTES
                      + 2 * (size_t)NROWS * sizeof(float)
                      + 3 * NSTATE * sizeof(float);       // ~143.6 MB
    if (ws_size < NEED) return;  // diagnostic: absmax-fail instead of fault

    char* w = (char*)d_ws;
    __hip_bfloat16* S0 = (__hip_bfloat16*)(w);
    __hip_bfloat16* S1 = (__hip_bfloat16*)(w + 1 * SL);
    __hip_bfloat16* S2 = (__hip_bfloat16*)(w + 2 * SL);
    __hip_bfloat16* S3 = (__hip_bfloat16*)(w + 3 * SL);
    __hip_bfloat16* S4 = (__hip_bfloat16*)(w + 4 * SL);
    __hip_bfloat16* WkB = (__hip_bfloat16*)(w + 5 * SL);
    __hip_bfloat16* WvB = WkB + DW;
    __hip_bfloat16* WrB = WvB + DW;
    __hip_bfloat16* WoB = WrB + DW;
    __hip_bfloat16* CrB = WoB + DW;
    __hip_bfloat16* CkB = CrB + DW;
    __hip_bfloat16* CvB = CkB + DH;
    float* meanB = (float*)(w + 5 * SL + WBYTES);
    float* rstdB = meanB + NROWS;
    float* SAb = rstdB + NROWS;
    float* SBb = SAb + NSTATE;
    float* SPb = SBb + NSTATE;

    const int EW_GRID = (int)(ND / 256);      // 49152
    const dim3 g768(NROWS / BM, DD / BN);     // (128, 6)
    const dim3 g1536(NROWS / BM, HHALF / BN); // (128, 12)
    const dim3 gwkv(DD / 256, PCH, BBATCH);   // (3, 16, 16)
    const int CB_W = DW / 4 / 256;            // 576
    const int CB_H = DH / 4 / 256;            // 2304

    // ---- weight conversion ----
    cvt_k<<<CB_W, 256, 0, stream>>>(Wk, WkB, DW);
    cvt_k<<<CB_W, 256, 0, stream>>>(Wv, WvB, DW);
    cvt_k<<<CB_W, 256, 0, stream>>>(Wr, WrB, DW);
    cvt_k<<<CB_W, 256, 0, stream>>>(Wo, WoB, DW);
    cvt_k<<<CB_W, 256, 0, stream>>>(Cr, CrB, DW);
    cvt_k<<<CB_H, 256, 0, stream>>>(Ck, CkB, DH);
    cvt_k<<<CB_H, 256, 0, stream>>>(Cv, CvB, DH);

    // ---- spatial mix ----
    ln_stats_k<float><<<NROWS, 256, 0, stream>>>(x, meanB, rstdB);
    mix_k<float, 3><<<EW_GRID, 256, 0, stream>>>(x, meanB, rstdB, ln1_g, ln1_b,
                                                 mu_k, mu_v, mu_r, S0, S1, S2);
    gemm_bt<0><<<g768, 256, 0, stream>>>(S0, WkB, DD, DD, DD, S3, nullptr, nullptr, nullptr, nullptr); // k
    gemm_bt<0><<<g768, 256, 0, stream>>>(S1, WvB, DD, DD, DD, S4, nullptr, nullptr, nullptr, nullptr); // v
    gemm_bt<1><<<g768, 256, 0, stream>>>(S2, WrB, DD, DD, DD, S0, nullptr, nullptr, nullptr, nullptr); // r=sigmoid
    wkv_passA<<<gwkv, 256, 0, stream>>>(w_log, S3, S4, SAb, SBb, SPb);
    wkv_scanj<<<(BBATCH * DD) / 256, 256, 0, stream>>>(w_log, SAb, SBb, SPb);
    wkv_passB<<<gwkv, 256, 0, stream>>>(w_log, u, S3, S4, S0, S1, SAb, SBb, SPb); // rw -> S1
    gemm_bt<2><<<g768, 256, 0, stream>>>(S1, WoB, DD, DD, DD, S2, nullptr, nullptr, nullptr, x);       // h = acc + x

    // ---- channel mix ----
    ln_stats_k<__hip_bfloat16><<<NROWS, 256, 0, stream>>>(S2, meanB, rstdB);
    mix_k<__hip_bfloat16, 2><<<EW_GRID, 256, 0, stream>>>(S2, meanB, rstdB, ln2_g, ln2_b,
                                                          cmu_k, nullptr, cmu_r, S0, nullptr, S3);
    gemm_bt<1><<<g768, 256, 0, stream>>>(S3, CrB, DD, DD, DD, S1, nullptr, nullptr, nullptr, nullptr); // cr=sigmoid
    // FFN in two 1536-wide halves; kk lives in S3+S4 (contiguous)
    __hip_bfloat16* kk = S3;
    gemm_bt<3><<<g1536, 256, 0, stream>>>(S0, CkB, DD, DD, HHALF,
                                          kk, nullptr, nullptr, nullptr, nullptr);
    gemm_bt<4><<<g768, 256, 0, stream>>>(kk, CvB, HHALF, HIDN, DD,
                                         nullptr, out, S1, S2, x);
    gemm_bt<3><<<g1536, 256, 0, stream>>>(S0, CkB + (size_t)HHALF * DD, DD, DD, HHALF,
                                          kk, nullptr, nullptr, nullptr, nullptr);
    gemm_bt<5><<<g768, 256, 0, stream>>>(kk, CvB + HHALF, HHALF, HIDN, DD,
                                         nullptr, out, S1, nullptr, nullptr);
}

// Round 7
// 580.051 us; speedup vs baseline: 1.4753x; 1.0599x over previous
//
#include <hip/hip_runtime.h>
#include <hip/hip_bf16.h>

// Problem constants (fixed by the reference)
#define DD   768
#define TT   1024
#define BBATCH 16
#define NROWS (BBATCH * TT)   // 16384
#define HIDN 3072
#define HHALF 1536
#define HH 32
#define WW 32
#define DW  (DD * DD)         // 589824
#define DH  (DD * HIDN)       // 2359296
#define CCH 64                // wkv chunk length
#define PCH (TT / CCH)        // 16 chunks

typedef float  floatx4 __attribute__((ext_vector_type(4)));
typedef __bf16 bf16x8  __attribute__((ext_vector_type(8)));

__device__ __forceinline__ float bf2f(__hip_bfloat16 v) { return __bfloat162float(v); }
__device__ __forceinline__ __hip_bfloat16 f2bf(float v) { return __float2bfloat16(v); }
__device__ __forceinline__ float toF(__hip_bfloat16 v) { return __bfloat162float(v); }
__device__ __forceinline__ float toF(float v) { return v; }

// global -> LDS direct DMA, 16 B per lane, dest = uniform base + lane*16
#define GL2LDS(gp, lp)  __builtin_amdgcn_global_load_lds(                     \
    (const __attribute__((address_space(1))) void*)(gp),                      \
    (__attribute__((address_space(3))) void*)(lp), 16, 0, 0)

// ---------------------------------------------------------------------------
// fp32 -> bf16 conversion of ALL weights in one dispatch (7 segments).
// dst layout: [Wk|Wv|Wr|Wo|Cr] (DW each) then [Ck|Cv] (DH each).
// ---------------------------------------------------------------------------
__global__ __launch_bounds__(256)
void cvt_all(const float* __restrict__ w0, const float* __restrict__ w1,
             const float* __restrict__ w2, const float* __restrict__ w3,
             const float* __restrict__ w4, const float* __restrict__ w5,
             const float* __restrict__ w6, __hip_bfloat16* __restrict__ dst)
{
    const int b = blockIdx.x;
    const float* s; size_t dofs; int rel;
    if (b < 2880) {            // 5 x 576 blocks of DW
        const int seg = b / 576; rel = b - seg * 576;
        s = seg == 0 ? w0 : seg == 1 ? w1 : seg == 2 ? w2 : seg == 3 ? w3 : w4;
        dofs = (size_t)seg * DW;
    } else if (b < 5184) {     // Ck: 2304 blocks
        rel = b - 2880; s = w5; dofs = 5ull * DW;
    } else {                   // Cv: 2304 blocks
        rel = b - 5184; s = w6; dofs = 5ull * DW + DH;
    }
    const int i = rel * 1024 + threadIdx.x * 4;
    const float4 v = *reinterpret_cast<const float4*>(s + i);
    __hip_bfloat16 o[4] = {f2bf(v.x), f2bf(v.y), f2bf(v.z), f2bf(v.w)};
    *reinterpret_cast<ushort4*>(&dst[dofs + i]) = *reinterpret_cast<const ushort4*>(o);
}

// ---------------------------------------------------------------------------
// Per-row LN stats: mean + rstd (768 cols, 256 threads x 3)
// ---------------------------------------------------------------------------
template <typename TIN>
__global__ __launch_bounds__(256)
void ln_stats_k(const TIN* __restrict__ x,
                float* __restrict__ mean, float* __restrict__ rstd)
{
    const int row = blockIdx.x, tid = threadIdx.x;
    const int lane = tid & 63, wid = tid >> 6;
    const TIN* xr = x + (size_t)row * DD;
    float s1 = 0.f, s2 = 0.f;
#pragma unroll
    for (int i = 0; i < 3; ++i) {
        const float v = toF(xr[tid + i * 256]);
        s1 += v; s2 += v * v;
    }
#pragma unroll
    for (int off = 32; off > 0; off >>= 1) {
        s1 += __shfl_down(s1, off);
        s2 += __shfl_down(s2, off);
    }
    __shared__ float sh[8];
    if (lane == 0) { sh[wid] = s1; sh[4 + wid] = s2; }
    __syncthreads();
    if (tid == 0) {
        s1 = sh[0] + sh[1] + sh[2] + sh[3];
        s2 = sh[4] + sh[5] + sh[6] + sh[7];
        const float m = s1 * (1.f / DD);
        mean[row] = m;
        rstd[row] = rsqrtf(s2 * (1.f / DD) - m * m + 1e-5f);
    }
}

// ---------------------------------------------------------------------------
// LN-on-the-fly + q_shift + token-mix, bf16 outputs (GEMM A operands)
// ---------------------------------------------------------------------------
template <typename TIN>
__device__ __forceinline__ float ln_at(const TIN* __restrict__ x,
                                       const float* __restrict__ mean,
                                       const float* __restrict__ rstd,
                                       const float* __restrict__ g,
                                       const float* __restrict__ b,
                                       int grow, int c)
{
    return (toF(x[(size_t)grow * DD + c]) - mean[grow]) * rstd[grow] * g[c] + b[c];
}

template <typename TIN, int NOUT>
__global__ __launch_bounds__(256)
void mix_k(const TIN* __restrict__ x,
           const float* __restrict__ mean, const float* __restrict__ rstd,
           const float* __restrict__ g, const float* __restrict__ b,
           const float* __restrict__ muk,
           const float* __restrict__ muv,   // unused if NOUT==2
           const float* __restrict__ mur,
           __hip_bfloat16* __restrict__ xk,
           __hip_bfloat16* __restrict__ xv, // unused if NOUT==2
           __hip_bfloat16* __restrict__ xr)
{
    const size_t idx = (size_t)blockIdx.x * 256 + threadIdx.x;
    const int c  = (int)(idx % DD);
    const int n  = (int)((idx / DD) % TT);
    const int bb = (int)(idx / ((size_t)DD * TT));
    const int y = n >> 5, xp = n & 31;
    const int grow = bb * TT + n;

    const float av = ln_at(x, mean, rstd, g, b, grow, c);

    const int grp = c / (DD / 4);
    int ny = y, nx = xp; bool ok;
    if      (grp == 0) { nx = xp - 1; ok = xp > 0;      }
    else if (grp == 1) { nx = xp + 1; ok = xp < WW - 1; }
    else if (grp == 2) { ny = y - 1;  ok = y > 0;       }
    else               { ny = y + 1;  ok = y < HH - 1;  }
    const float sx = ok ? ln_at(x, mean, rstd, g, b, bb * TT + ny * WW + nx, c) : 0.f;

    const float mk = muk[c], mr = mur[c];
    xk[idx] = f2bf(av * mk + sx * (1.f - mk));
    xr[idx] = f2bf(av * mr + sx * (1.f - mr));
    if (NOUT == 3) {
        const float mv = muv[c];
        xv[idx] = f2bf(av * mv + sx * (1.f - mv));
    }
}

// ---------------------------------------------------------------------------
// GEMM core: 128x128 tile, 4 waves (2x2 of 64x64), BK=64, global_load_lds
// staging with XOR col-group swizzle (round-6 verified: 0 bank conflicts).
// lds layout: A tile at [0, 8192), B tile at [8192, 16384) ushorts.
// ---------------------------------------------------------------------------
#define BM 128
#define BN 128
#define BKK 64

__device__ __forceinline__ void gemm_core(
    const __hip_bfloat16* __restrict__ A, const __hip_bfloat16* __restrict__ W,
    int K, int Wstr, int bm, int bn, unsigned short* lds, floatx4 acc[4][4])
{
    const int tid  = threadIdx.x;
    const int lane = tid & 63, wid = tid >> 6;
    const int l15  = lane & 15, quad = lane >> 4;
    const int m0   = (wid & 1) * 64;
    const int n0   = (wid >> 1) * 64;
    const int srow  = lane >> 3;            // 0..7
    const int gcolg = (lane & 7) ^ srow;    // swizzled col-group to fetch
    const int s0    = wid * 4;
    const int swzbase = l15 & 7;

    for (int k0 = 0; k0 < K; k0 += BKK) {
#pragma unroll
        for (int t = 0; t < 4; ++t) {
            const int s   = s0 + t;
            const int row = s * 8 + srow;
            GL2LDS(A + (size_t)(bm * BM + row) * K    + k0 + gcolg * 8,
                   &lds[s * 512]);
            GL2LDS(W + (size_t)(bn * BN + row) * Wstr + k0 + gcolg * 8,
                   &lds[8192 + s * 512]);
        }
        __syncthreads();
#pragma unroll
        for (int kk = 0; kk < BKK; kk += 32) {
            const int swz = (((kk >> 3) + quad) ^ swzbase) * 8;
            bf16x8 af[4], bfr[4];
#pragma unroll
            for (int i = 0; i < 4; ++i)
                af[i] = *reinterpret_cast<const bf16x8*>(
                    &lds[(m0 + i * 16 + l15) * BKK + swz]);
#pragma unroll
            for (int j = 0; j < 4; ++j)
                bfr[j] = *reinterpret_cast<const bf16x8*>(
                    &lds[8192 + (n0 + j * 16 + l15) * BKK + swz]);
#pragma unroll
            for (int i = 0; i < 4; ++i)
#pragma unroll
                for (int j = 0; j < 4; ++j)
                    acc[i][j] = __builtin_amdgcn_mfma_f32_16x16x32_bf16(
                        af[i], bfr[j], acc[i][j], 0, 0, 0);
        }
        __syncthreads();
    }
}

// Wave-private LDS transpose of one 16-row acc band -> 16 contiguous cols
// per lane (row_l = lane>>2, cols cb..cb+15). Wave-internal DS ops are
// in-order, so no barrier is needed; LDS tiles are dead after the K-loop's
// final barrier. Stride 68 floats keeps float4 alignment + <=2-way banks.
__device__ __forceinline__ void xpose_band(const floatx4 accRow[4], float* scr,
                                           int lane, float cv[16])
{
    const int l15 = lane & 15, quad = lane >> 4;
#pragma unroll
    for (int j = 0; j < 4; ++j)
#pragma unroll
        for (int r = 0; r < 4; ++r)
            scr[(quad * 4 + r) * 68 + j * 16 + l15] = accRow[j][r];
    const int row_l = lane >> 2, cb = (lane & 3) * 16;
#pragma unroll
    for (int q = 0; q < 4; ++q)
        *reinterpret_cast<float4*>(&cv[q * 4]) =
            *reinterpret_cast<const float4*>(&scr[row_l * 68 + cb + q * 4]);
}

// MODE: 1=bf16(sigmoid), 2=bf16(acc + xf32), 3=bf16(relu^2),
//       4=f32 out = h + s*acc + x, 5=f32 out += s*acc
template <int MODE>
__global__ __launch_bounds__(256, 2)
void gemm_bt(const __hip_bfloat16* __restrict__ A,
             const __hip_bfloat16* __restrict__ W,
             int K, int Wstr, int Nn,
             __hip_bfloat16* __restrict__ outB,
             float* __restrict__ outF,
             const __hip_bfloat16* __restrict__ auxS,  // sigmoid gate [4,5]
             const __hip_bfloat16* __restrict__ auxH,  // h bf16       [4]
             const float* __restrict__ auxX)           // x fp32       [2,4]
{
    __shared__ __align__(16) unsigned short lds[16384];  // 32 KB
    const int bm = blockIdx.x, bn = blockIdx.y;
    const int tid = threadIdx.x, lane = tid & 63, wid = tid >> 6;
    const int m0 = (wid & 1) * 64, n0 = (wid >> 1) * 64;

    floatx4 acc[4][4];
#pragma unroll
    for (int i = 0; i < 4; ++i)
#pragma unroll
        for (int j = 0; j < 4; ++j)
            acc[i][j] = floatx4{0.f, 0.f, 0.f, 0.f};

    gemm_core(A, W, K, Wstr, bm, bn, lds, acc);

    float* scr = reinterpret_cast<float*>(lds) + wid * 1088;  // 4352 B/wave
    const int row_l = lane >> 2, cb = (lane & 3) * 16;
#pragma unroll
    for (int i = 0; i < 4; ++i) {
        float cv[16];
        xpose_band(acc[i], scr, lane, cv);
        const int grow = bm * BM + m0 + i * 16 + row_l;
        const int gcol = bn * BN + n0 + cb;
        const size_t idx = (size_t)grow * Nn + gcol;
        if (MODE == 1 || MODE == 3) {
            __hip_bfloat16 ob[16];
#pragma unroll
            for (int e = 0; e < 16; ++e) {
                float v = cv[e];
                if (MODE == 1) v = 1.f / (1.f + __expf(-v));
                else { v = fmaxf(v, 0.f); v = v * v; }
                ob[e] = f2bf(v);
            }
            *reinterpret_cast<uint4*>(&outB[idx])     = *reinterpret_cast<const uint4*>(&ob[0]);
            *reinterpret_cast<uint4*>(&outB[idx + 8]) = *reinterpret_cast<const uint4*>(&ob[8]);
        } else if (MODE == 2) {
            float xv[16];
#pragma unroll
            for (int q = 0; q < 4; ++q)
                *reinterpret_cast<float4*>(&xv[q * 4]) =
                    *reinterpret_cast<const float4*>(&auxX[idx + q * 4]);
            __hip_bfloat16 ob[16];
#pragma unroll
            for (int e = 0; e < 16; ++e) ob[e] = f2bf(cv[e] + xv[e]);
            *reinterpret_cast<uint4*>(&outB[idx])     = *reinterpret_cast<const uint4*>(&ob[0]);
            *reinterpret_cast<uint4*>(&outB[idx + 8]) = *reinterpret_cast<const uint4*>(&ob[8]);
        } else if (MODE == 4) {
            unsigned short hs[16], ss[16]; float xv[16], ov[16];
            *reinterpret_cast<uint4*>(&hs[0]) = *reinterpret_cast<const uint4*>(&auxH[idx]);
            *reinterpret_cast<uint4*>(&hs[8]) = *reinterpret_cast<const uint4*>(&auxH[idx + 8]);
            *reinterpret_cast<uint4*>(&ss[0]) = *reinterpret_cast<const uint4*>(&auxS[idx]);
            *reinterpret_cast<uint4*>(&ss[8]) = *reinterpret_cast<const uint4*>(&auxS[idx + 8]);
#pragma unroll
            for (int q = 0; q < 4; ++q)
                *reinterpret_cast<float4*>(&xv[q * 4]) =
                    *reinterpret_cast<const float4*>(&auxX[idx + q * 4]);
#pragma unroll
            for (int e = 0; e < 16; ++e)
                ov[e] = bf2f(__hip_bfloat16_raw{hs[e]})
                      + bf2f(__hip_bfloat16_raw{ss[e]}) * cv[e] + xv[e];
#pragma unroll
            for (int q = 0; q < 4; ++q)
                *reinterpret_cast<float4*>(&outF[idx + q * 4]) =
                    *reinterpret_cast<const float4*>(&ov[q * 4]);
        } else {  // MODE 5: out += s*acc
            unsigned short ss[16]; float ov[16];
            *reinterpret_cast<uint4*>(&ss[0]) = *reinterpret_cast<const uint4*>(&auxS[idx]);
            *reinterpret_cast<uint4*>(&ss[8]) = *reinterpret_cast<const uint4*>(&auxS[idx + 8]);
#pragma unroll
            for (int q = 0; q < 4; ++q)
                *reinterpret_cast<float4*>(&ov[q * 4]) =
                    *reinterpret_cast<const float4*>(&outF[idx + q * 4]);
#pragma unroll
            for (int e = 0; e < 16; ++e)
                ov[e] += bf2f(__hip_bfloat16_raw{ss[e]}) * cv[e];
#pragma unroll
            for (int q = 0; q < 4; ++q)
                *reinterpret_cast<float4*>(&outF[idx + q * 4]) =
                    *reinterpret_cast<const float4*>(&ov[q * 4]);
        }
    }
}

// Batched QKV: z=0 -> k=xk@Wk^T, z=1 -> v, z=2 -> r=sigmoid(xr@Wr^T)
__global__ __launch_bounds__(256, 2)
void gemm_qkv(const __hip_bfloat16* __restrict__ A0, const __hip_bfloat16* __restrict__ A1,
              const __hip_bfloat16* __restrict__ A2,
              const __hip_bfloat16* __restrict__ W0, const __hip_bfloat16* __restrict__ W1,
              const __hip_bfloat16* __restrict__ W2,
              __hip_bfloat16* __restrict__ O0, __hip_bfloat16* __restrict__ O1,
              __hip_bfloat16* __restrict__ O2)
{
    __shared__ __align__(16) unsigned short lds[16384];
    const int z = blockIdx.z;
    const __hip_bfloat16* A = z == 0 ? A0 : z == 1 ? A1 : A2;
    const __hip_bfloat16* W = z == 0 ? W0 : z == 1 ? W1 : W2;
    __hip_bfloat16*       O = z == 0 ? O0 : z == 1 ? O1 : O2;
    const int bm = blockIdx.x, bn = blockIdx.y;
    const int tid = threadIdx.x, lane = tid & 63, wid = tid >> 6;
    const int m0 = (wid & 1) * 64, n0 = (wid >> 1) * 64;

    floatx4 acc[4][4];
#pragma unroll
    for (int i = 0; i < 4; ++i)
#pragma unroll
        for (int j = 0; j < 4; ++j)
            acc[i][j] = floatx4{0.f, 0.f, 0.f, 0.f};

    gemm_core(A, W, DD, DD, bm, bn, lds, acc);

    float* scr = reinterpret_cast<float*>(lds) + wid * 1088;
    const int row_l = lane >> 2, cb = (lane & 3) * 16;
#pragma unroll
    for (int i = 0; i < 4; ++i) {
        float cv[16];
        xpose_band(acc[i], scr, lane, cv);
        const int grow = bm * BM + m0 + i * 16 + row_l;
        const int gcol = bn * BN + n0 + cb;
        const size_t idx = (size_t)grow * DD + gcol;
        __hip_bfloat16 ob[16];
#pragma unroll
        for (int e = 0; e < 16; ++e) {
            float v = cv[e];
            if (z == 2) v = 1.f / (1.f + __expf(-v));
            ob[e] = f2bf(v);
        }
        *reinterpret_cast<uint4*>(&O[idx])     = *reinterpret_cast<const uint4*>(&ob[0]);
        *reinterpret_cast<uint4*>(&O[idx + 8]) = *reinterpret_cast<const uint4*>(&ob[8]);
    }
}

// ---------------------------------------------------------------------------
// WKV parallel scan over T (chunked two-pass; round-5 verified).
// ---------------------------------------------------------------------------
__global__ __launch_bounds__(256)
void wkv_passA(const float* __restrict__ w_log,
               const __hip_bfloat16* __restrict__ k,
               const __hip_bfloat16* __restrict__ v,
               float* __restrict__ SA, float* __restrict__ SB,
               float* __restrict__ SP)
{
    const int c  = blockIdx.x * 256 + threadIdx.x;  // 0..767
    const int j  = blockIdx.y;                      // chunk
    const int bb = blockIdx.z;                      // batch
    const float w = -__expf(w_log[c]);
    const size_t base = ((size_t)bb * TT + j * CCH) * DD + c;
    float a = 0.f, b = 0.f, p = -1e30f;
#pragma unroll 4
    for (int t = 0; t < CCH; ++t) {
        const size_t o = base + (size_t)t * DD;
        const float kt = bf2f(k[o]);
        const float vt = bf2f(v[o]);
        const float ww2 = p + w;
        const float p2  = fmaxf(ww2, kt);
        const float e1  = __expf(ww2 - p2);
        const float e2  = __expf(kt - p2);
        a = e1 * a + e2 * vt;
        b = e1 * b + e2;
        p = p2;
    }
    const size_t si = ((size_t)bb * PCH + j) * DD + c;
    SA[si] = a; SB[si] = b; SP[si] = p;
}

__global__ __launch_bounds__(256)
void wkv_scanj(const float* __restrict__ w_log,
               float* __restrict__ SA, float* __restrict__ SB,
               float* __restrict__ SP)
{
    const int idx = blockIdx.x * 256 + threadIdx.x;  // 0..B*D-1
    const int c = idx % DD, bb = idx / DD;
    const float wC = -__expf(w_log[c]) * (float)CCH;  // decay over one chunk
    float a = 0.f, b = 0.f, p = -1e30f;
#pragma unroll
    for (int j = 0; j < PCH; ++j) {
        const size_t si = ((size_t)bb * PCH + j) * DD + c;
        const float aj = SA[si], bj = SB[si], pj = SP[si];
        SA[si] = a; SB[si] = b; SP[si] = p;   // exclusive prefix (chunk input)
        const float pd = p + wC;
        const float pn = fmaxf(pd, pj);
        const float e1 = __expf(pd - pn);
        const float e2 = __expf(pj - pn);
        a = e1 * a + e2 * aj;
        b = e1 * b + e2 * bj;
        p = pn;
    }
}

__global__ __launch_bounds__(256)
void wkv_passB(const float* __restrict__ w_log, const float* __restrict__ u,
               const __hip_bfloat16* __restrict__ k,
               const __hip_bfloat16* __restrict__ v,
               const __hip_bfloat16* __restrict__ r,
               __hip_bfloat16* __restrict__ rw,
               const float* __restrict__ SA, const float* __restrict__ SB,
               const float* __restrict__ SP)
{
    const int c  = blockIdx.x * 256 + threadIdx.x;
    const int j  = blockIdx.y;
    const int bb = blockIdx.z;
    const float w  = -__expf(w_log[c]);
    const float uu = u[c];
    const size_t si = ((size_t)bb * PCH + j) * DD + c;
    float aa = SA[si], bbv = SB[si], pp = SP[si];
    const size_t base = ((size_t)bb * TT + j * CCH) * DD + c;
#pragma unroll 4
    for (int t = 0; t < CCH; ++t) {
        const size_t o = base + (size_t)t * DD;
        const float kt = bf2f(k[o]);
        const float vt = bf2f(v[o]);
        const float rt = bf2f(r[o]);
        const float ww = uu + kt;
        const float p  = fmaxf(pp, ww);
        const float e1 = __expf(pp - p);
        const float e2 = __expf(ww - p);
        const float ov = __fdividef(e1 * aa + e2 * vt, e1 * bbv + e2);
        rw[o] = f2bf(rt * ov);
        const float ww2 = pp + w;
        const float p2  = fmaxf(ww2, kt);
        const float e1b = __expf(ww2 - p2);
        const float e2b = __expf(kt - p2);
        aa  = e1b * aa + e2b * vt;
        bbv = e1b * bbv + e2b;
        pp  = p2;
    }
}

// ---------------------------------------------------------------------------
extern "C" void kernel_launch(void* const* d_in, const int* in_sizes, int n_in,
                              void* d_out, int out_size, void* d_ws, size_t ws_size,
                              hipStream_t stream)
{
    (void)in_sizes; (void)n_in; (void)out_size;
    const float* x     = (const float*)d_in[0];
    // d_in[1]=H, d_in[2]=W (compile-time constants 32x32)
    const float* ln1_g = (const float*)d_in[3];
    const float* ln1_b = (const float*)d_in[4];
    const float* ln2_g = (const float*)d_in[5];
    const float* ln2_b = (const float*)d_in[6];
    const float* mu_k  = (const float*)d_in[7];
    const float* mu_v  = (const float*)d_in[8];
    const float* mu_r  = (const float*)d_in[9];
    const float* w_log = (const float*)d_in[10];
    const float* u     = (const float*)d_in[11];
    const float* Wk    = (const float*)d_in[12];
    const float* Wv    = (const float*)d_in[13];
    const float* Wr    = (const float*)d_in[14];
    const float* Wo    = (const float*)d_in[15];
    const float* cmu_k = (const float*)d_in[16];
    const float* cmu_r = (const float*)d_in[17];
    const float* Ck    = (const float*)d_in[18];
    const float* Cv    = (const float*)d_in[19];
    const float* Cr    = (const float*)d_in[20];
    float* out = (float*)d_out;

    // ---- workspace: 5 bf16 ND slots + bf16 weights + stats + scan states
    const size_t ND = (size_t)NROWS * DD;   // 12,582,912 elements
    const size_t SL = ND * 2;               // 25,165,824 B per bf16 slot
    const size_t WBYTES = (size_t)(5 * DW + 2 * DH) * 2;  // 15,335,424
    const size_t NSTATE = (size_t)BBATCH * PCH * DD;      // 196,608
    const size_t NEED = 5 * SL + WBYTES
                      + 2 * (size_t)NROWS * sizeof(float)
                      + 3 * NSTATE * sizeof(float);       // ~143.6 MB
    if (ws_size < NEED) return;  // diagnostic: absmax-fail instead of fault

    char* w = (char*)d_ws;
    __hip_bfloat16* S0 = (__hip_bfloat16*)(w);
    __hip_bfloat16* S1 = (__hip_bfloat16*)(w + 1 * SL);
    __hip_bfloat16* S2 = (__hip_bfloat16*)(w + 2 * SL);
    __hip_bfloat16* S3 = (__hip_bfloat16*)(w + 3 * SL);
    __hip_bfloat16* S4 = (__hip_bfloat16*)(w + 4 * SL);
    __hip_bfloat16* WB  = (__hip_bfloat16*)(w + 5 * SL);
    __hip_bfloat16* WkB = WB;
    __hip_bfloat16* WvB = WB + 1ull * DW;
    __hip_bfloat16* WrB = WB + 2ull * DW;
    __hip_bfloat16* WoB = WB + 3ull * DW;
    __hip_bfloat16* CrB = WB + 4ull * DW;
    __hip_bfloat16* CkB = WB + 5ull * DW;
    __hip_bfloat16* CvB = CkB + DH;
    float* meanB = (float*)(w + 5 * SL + WBYTES);
    float* rstdB = meanB + NROWS;
    float* SAb = rstdB + NROWS;
    float* SBb = SAb + NSTATE;
    float* SPb = SBb + NSTATE;

    const int EW_GRID = (int)(ND / 256);      // 49152
    const dim3 g768(NROWS / BM, DD / BN);     // (128, 6)
    const dim3 g1536(NROWS / BM, HHALF / BN); // (128, 12)
    const dim3 gqkv(NROWS / BM, DD / BN, 3);  // (128, 6, 3)
    const dim3 gwkv(DD / 256, PCH, BBATCH);   // (3, 16, 16)

    // ---- weight conversion (single dispatch) ----
    cvt_all<<<7488, 256, 0, stream>>>(Wk, Wv, Wr, Wo, Cr, Ck, Cv, WB);

    // ---- spatial mix ----
    ln_stats_k<float><<<NROWS, 256, 0, stream>>>(x, meanB, rstdB);
    mix_k<float, 3><<<EW_GRID, 256, 0, stream>>>(x, meanB, rstdB, ln1_g, ln1_b,
                                                 mu_k, mu_v, mu_r, S0, S1, S2);
    // k -> S3, v -> S4, r -> S0 (overwrites xk after use within same dispatch? No:
    // z=0 reads S0 only; z=2 writes S0. Different blocks may race!  Use distinct
    // output: r -> S2 is unsafe (xr input). Route r to a non-input slot: S1 is
    // xv input... All 3 inputs S0,S1,S2 are live for the whole dispatch, so r
    // must land elsewhere -> write r into S4? v also writes S4. Solution:
    // k->S3, v->S4, r->(reuse of nothing free)... keep r in its own region:
    // stats area is too small. Simplest safe: r -> S2 is WRONG; instead run r
    // via the batched kernel into a dedicated slot carved from kk space: S3
    // holds k, S4 holds v, and r goes to S2 ONLY IF xr no longer needed - but
    // z=2 itself reads xr. Since blocks of z=2 both read xr(S2) and write
    // r(S2) at DIFFERENT (row,col) tiles, a race exists. So: r -> scratch at
    // S3+? No. Use separate dispatch-free trick: swap operands so r output
    // overwrites xk (S0): z=0 (k) reads S0 too. Race again.
    // => keep QKV batched but give r its own buffer: reuse SA/SB/SP? too small.
    // Final: batch only k,v (z=0,1) is pointless; instead batch all 3 with
    // r -> S4 + v -> S3 + k -> ... all 3 outputs need 3 slots: S3, S4 and one
    // more. S2 (xr) is consumed by this dispatch; S0/S1 consumed too. After
    // this dispatch xk/xv/xr are all dead. Outputs: k,v,r = 3 slots among
    // {S0,S1,S2} impossible (inputs), so outputs = S3, S4 + one of the input
    // slots is required. NOT SAFE. => revert to r as separate dispatch AFTER
    // k,v batched (then xk,xv dead, r can safely write S0... but z-batched
    // k,v dispatch reads S0,S1 and writes S3,S4: safe!).
    gemm_qkv<<<dim3(NROWS / BM, DD / BN, 2), 256, 0, stream>>>(
        S0, S1, nullptr, WkB, WvB, nullptr, S3, S4, nullptr);       // k->S3, v->S4
    gemm_bt<1><<<g768, 256, 0, stream>>>(S2, WrB, DD, DD, DD, S0, nullptr,
                                         nullptr, nullptr, nullptr); // r=sigmoid -> S0
    wkv_passA<<<gwkv, 256, 0, stream>>>(w_log, S3, S4, SAb, SBb, SPb);
    wkv_scanj<<<(BBATCH * DD) / 256, 256, 0, stream>>>(w_log, SAb, SBb, SPb);
    wkv_passB<<<gwkv, 256, 0, stream>>>(w_log, u, S3, S4, S0, S1, SAb, SBb, SPb); // rw -> S1
    gemm_bt<2><<<g768, 256, 0, stream>>>(S1, WoB, DD, DD, DD, S2, nullptr,
                                         nullptr, nullptr, x);       // h = acc + x -> S2

    // ---- channel mix ----
    ln_stats_k<__hip_bfloat16><<<NROWS, 256, 0, stream>>>(S2, meanB, rstdB);
    mix_k<__hip_bfloat16, 2><<<EW_GRID, 256, 0, stream>>>(S2, meanB, rstdB, ln2_g, ln2_b,
                                                          cmu_k, nullptr, cmu_r, S0, nullptr, S3);
    gemm_bt<1><<<g768, 256, 0, stream>>>(S3, CrB, DD, DD, DD, S1, nullptr,
                                         nullptr, nullptr, nullptr); // cr=sigmoid -> S1
    // FFN in two 1536-wide halves; kk lives in S3+S4 (contiguous)
    __hip_bfloat16* kk = S3;
    gemm_bt<3><<<g1536, 256, 0, stream>>>(S0, CkB, DD, DD, HHALF,
                                          kk, nullptr, nullptr, nullptr, nullptr);
    gemm_bt<4><<<g768, 256, 0, stream>>>(kk, CvB, HHALF, HIDN, DD,
                                         nullptr, out, S1, S2, x);
    gemm_bt<3><<<g1536, 256, 0, stream>>>(S0, CkB + (size_t)HHALF * DD, DD, DD, HHALF,
                                          kk, nullptr, nullptr, nullptr, nullptr);
    gemm_bt<5><<<g768, 256, 0, stream>>>(kk, CvB + HHALF, HHALF, HIDN, DD,
                                         nullptr, out, S1, nullptr, nullptr);
}